// Round 10
// baseline (258.890 us; speedup 1.0000x reference)
//
#include <hip/hip_runtime.h>
#include <hip/hip_bf16.h>

#define HID 1024
#define INTER 4096
#define NE 8
#define NTOK 2048
#define MAXROWS 5120   // 4096 pairs + 8*127 pad, rounded up

typedef __attribute__((ext_vector_type(8))) short short8v;
typedef __attribute__((ext_vector_type(4))) short short4v;
typedef __attribute__((ext_vector_type(4))) float f32x4;

__device__ __forceinline__ unsigned short f2bf(float f) {
  unsigned int u = __builtin_bit_cast(unsigned int, f);
  u = (u + 0x7FFFu + ((u >> 16) & 1u)) >> 16;
  return (unsigned short)u;
}
__device__ __forceinline__ float bf2f(unsigned short s) {
  unsigned int u = ((unsigned int)s) << 16;
  return __builtin_bit_cast(float, u);
}

typedef const __attribute__((address_space(1))) unsigned int* gas_t;
typedef __attribute__((address_space(3))) unsigned int* las_t;
__device__ __forceinline__ void gld16(const unsigned short* g, unsigned short* l) {
  __builtin_amdgcn_global_load_lds((gas_t)(const void*)g, (las_t)(void*)l, 16, 0, 0);
}

// ------- transpose+convert one 64x64 tile: in [z][R][C] f32 -> out [z][C][R] bf16 -------
// t is a 64*65 float scratch in LDS.
__device__ __forceinline__ void tconv_tile(const float* __restrict__ in,
                                           unsigned short* __restrict__ out,
                                           int R, int C, int bx, int by, int z,
                                           float* __restrict__ t) {
  const int r0 = by * 64, c0 = bx * 64;
  const int tr = threadIdx.x / 16;
  const int tc = (threadIdx.x % 16) * 4;
  const float* ip = in + ((size_t)z * R + r0) * (size_t)C + c0;
#pragma unroll
  for (int p = 0; p < 4; ++p) {
    f32x4 v = *(const f32x4*)&ip[(size_t)(p * 16 + tr) * C + tc];
    t[(p * 16 + tr) * 65 + tc + 0] = v[0];
    t[(p * 16 + tr) * 65 + tc + 1] = v[1];
    t[(p * 16 + tr) * 65 + tc + 2] = v[2];
    t[(p * 16 + tr) * 65 + tc + 3] = v[3];
  }
  __syncthreads();
  unsigned short* op = out + ((size_t)z * C + c0) * (size_t)R + r0;
#pragma unroll
  for (int p = 0; p < 4; ++p) {
    int c = p * 16 + tr;
    unsigned int a0 = (unsigned int)f2bf(t[(tc + 0) * 65 + c]) |
                      ((unsigned int)f2bf(t[(tc + 1) * 65 + c]) << 16);
    unsigned int a1 = (unsigned int)f2bf(t[(tc + 2) * 65 + c]) |
                      ((unsigned int)f2bf(t[(tc + 3) * 65 + c]) << 16);
    uint2 val; val.x = a0; val.y = a1;
    *(uint2*)&op[(size_t)c * R + tc] = val;
  }
}

// ---------------- prep: convx (2048 blocks) + tconv1 (8192) + gating (2048) ----------------
__global__ __launch_bounds__(256) void prep_kernel(const float* __restrict__ x,
                                                   const float* __restrict__ W1,
                                                   const float* __restrict__ wg,
                                                   unsigned short* __restrict__ xb,
                                                   unsigned short* __restrict__ w1t,
                                                   int* __restrict__ tok_e,
                                                   float* __restrict__ tok_w) {
  __shared__ float sh[64 * 65];
  int bid = blockIdx.x;
  if (bid < 2048) {   // ---- convx: x fp32 -> bf16 ----
    size_t i = (size_t)bid * 256 + threadIdx.x;
    f32x4 v = *(const f32x4*)&x[i * 4];
    uint2 r;
    r.x = (unsigned int)f2bf(v[0]) | ((unsigned int)f2bf(v[1]) << 16);
    r.y = (unsigned int)f2bf(v[2]) | ((unsigned int)f2bf(v[3]) << 16);
    *(uint2*)&xb[i * 4] = r;
    return;
  }
  bid -= 2048;
  if (bid < 8192) {   // ---- tconv1: W1 [E][H][I] -> w1t [E][I][H] ----
    tconv_tile(W1, w1t, HID, INTER, bid % 64, (bid / 64) % 16, bid / 1024, sh);
    return;
  }
  bid -= 8192;
  {   // ---- gating for token t = bid ----
    const int t = bid;
    float acc[NE];
#pragma unroll
    for (int e = 0; e < NE; ++e) acc[e] = 0.f;
    for (int k = threadIdx.x; k < HID; k += 256) {
      float xv = x[(size_t)t * HID + k];
#pragma unroll
      for (int e = 0; e < NE; ++e) acc[e] += xv * wg[e * HID + k];
    }
#pragma unroll
    for (int e = 0; e < NE; ++e) {
#pragma unroll
      for (int off = 32; off >= 1; off >>= 1) acc[e] += __shfl_xor(acc[e], off, 64);
    }
    float* red = sh;   // [4][NE]
    const int wave = threadIdx.x >> 6, lane = threadIdx.x & 63;
    if (lane == 0) {
#pragma unroll
      for (int e = 0; e < NE; ++e) red[wave * NE + e] = acc[e];
    }
    __syncthreads();
    if (threadIdx.x == 0) {
      float l[NE];
#pragma unroll
      for (int e = 0; e < NE; ++e)
        l[e] = red[0 * NE + e] + red[1 * NE + e] + red[2 * NE + e] + red[3 * NE + e];
      int i0 = 0;
#pragma unroll
      for (int e = 1; e < NE; ++e) if (l[e] > l[i0]) i0 = e;
      int i1 = -1;
#pragma unroll
      for (int e = 0; e < NE; ++e) {
        if (e == i0) continue;
        if (i1 < 0 || l[e] > l[i1]) i1 = e;
      }
      float e1 = __expf(l[i1] - l[i0]);
      float w0 = 1.f / (1.f + e1);
      tok_e[t * 2 + 0] = i0;
      tok_e[t * 2 + 1] = i1;
      tok_w[t * 2 + 0] = w0;
      tok_w[t * 2 + 1] = 1.f - w0;
    }
  }
}

// ---------------- routing: per-expert compaction (deterministic, single block) ----------------
__global__ __launch_bounds__(512) void routing_kernel(const int* __restrict__ tok_e,
                                                      int* __restrict__ list_tok,
                                                      int* __restrict__ tok_gslot,
                                                      int* __restrict__ offs_out) {
  __shared__ int cnts[NE];
  __shared__ int offs_s[NE + 1];
  const int e = threadIdx.x >> 6, lane = threadIdx.x & 63;
  int c = 0;
  for (int base = 0; base < NTOK; base += 64) {
    int tok = base + lane;
    int e0 = tok_e[tok * 2], e1 = tok_e[tok * 2 + 1];
    bool m = (e0 == e) || (e1 == e);
    unsigned long long mask = __ballot(m);
    c += __popcll(mask);
  }
  if (lane == 0) cnts[e] = c;
  __syncthreads();
  if (threadIdx.x == 0) {
    int o = 0;
    for (int i = 0; i < NE; ++i) { offs_s[i] = o; o += (cnts[i] + 127) & ~127; }
    offs_s[NE] = o;
    for (int i = 0; i <= NE; ++i) offs_out[i] = offs_s[i];
  }
  __syncthreads();
  const int off = offs_s[e];
  int run = 0;
  for (int base = 0; base < NTOK; base += 64) {
    int tok = base + lane;
    int e0 = tok_e[tok * 2], e1 = tok_e[tok * 2 + 1];
    bool m = (e0 == e) || (e1 == e);
    unsigned long long mask = __ballot(m);
    int pos = run + __popcll(mask & ((1ull << lane) - 1ull));
    if (m) {
      int gs = off + pos;
      list_tok[gs] = tok;
      tok_gslot[tok * 2 + ((e0 == e) ? 0 : 1)] = gs;
    }
    run += __popcll(mask);
  }
  const int cnt = cnts[e];
  const int padded = (cnt + 127) & ~127;
  for (int p = cnt + lane; p < padded; p += 64) list_tok[off + p] = 0;
}

// ---- grouped GEMM: 128x128 block, 4 waves, WAVE-PRIVATE LDS, NO BARRIERS in K-loop ----
// Each wave owns a private double-buffered (A 64x32 + B 64x32) bf16 tile pair, staged by its
// OWN 8 gld16 per K-step. vmcnt is per-wave FIFO -> no cross-wave hazard exists at all.
// Waves free-run and skew, so MFMA / ds_read / staging of different waves overlap at the
// SIMD level (the overlap the barrier convoy prevented in rounds 2-9).
// Chunk-XOR swizzle as verified (0 bank conflicts): chunk c of row r at c ^ ((r>>1)&3),
// via pre-swizzled global source + swizzled read offsets.
// TCONVN>0: blocks past the GEMM grid transpose W2 (co-scheduled independent work).
// FIRST: out = bf16 h with bias+GELU; else: out = bf16 partials[ks][row][col] (no bias).
template <int KTOT, int NTOT, bool FIRST, int NSPLIT, int TCONVN>
__global__ __launch_bounds__(256, 2) void moe_gemm(const unsigned short* __restrict__ Abase,
                                                   const unsigned short* __restrict__ Bbase,
                                                   const float* __restrict__ bias,
                                                   const int* __restrict__ list_tok,
                                                   const int* __restrict__ offs,
                                                   void* __restrict__ outp,
                                                   const float* __restrict__ W2f,
                                                   unsigned short* __restrict__ w2t) {
  constexpr int KS = KTOT / NSPLIT;   // K elems per slice
  constexpr int NT = KS / 32;         // K-steps (BK=32)
  static_assert(NT >= 4 && (NT & 1) == 0, "NT must be even");
  constexpr int nM = MAXROWS / 128;
  constexpr int nN = NTOT / 128;
  constexpr int NWG_GEMM = nN * nM * NSPLIT;
  // [wave][slot][A/B][64 rows x 32 k] = 4 x 2 x 2 x 4KB = 64KB
  __shared__ __align__(16) unsigned short lds[4][2][2][2048];

  if (TCONVN != 0 && blockIdx.x >= NWG_GEMM) {
    // tconv2: W2 [E][I][H] -> w2t [E][H][I]  (R=INTER, C=HID)
    int t = blockIdx.x - NWG_GEMM;
    tconv_tile(W2f, w2t, INTER, HID, t % 16, (t / 16) % 64, t / 1024,
               (float*)&lds[0][0][0][0]);
    return;
  }

  int wg = blockIdx.x;
  wg = (wg & 7) * (NWG_GEMM >> 3) + (wg >> 3);   // bijective XCD swizzle (NWG_GEMM % 8 == 0)
  const int ks = (NSPLIT > 1) ? (wg / (nM * nN)) : 0;
  const int rem = wg % (nM * nN);
  const int mt = rem % nM;                  // m fastest: neighbors share B panel in L2
  const int nt = rem / nM;
  const int grow0 = mt * 128;
  if (grow0 >= offs[NE]) return;
  int e = 0;
#pragma unroll
  for (int i = 1; i < NE; ++i) if (grow0 >= offs[i]) e = i;
  const int n0 = nt * 128;
  const int k0 = ks * KS;

  const int tid = threadIdx.x;
  const int wave = tid >> 6, lane = tid & 63;
  const int wm = wave >> 1, wn = wave & 1;   // wave's 64x64 output quadrant

  // --- staging: per-wave private tiles. Issue i covers rows [i*16, i*16+16).
  // Lane l -> row_local i*16 + (l>>2), chunk (l&3); source chunk pre-swizzled.
  const int rl = lane >> 2;
  const int sc = (((lane & 3) ^ ((lane >> 3) & 3)) * 8);  // shorts
  const unsigned short* ag[4];
  const unsigned short* bg[4];
#pragma unroll
  for (int i = 0; i < 4; ++i) {
    const int arl = wm * 64 + i * 16 + rl;   // row within the block's 128-row A tile
    size_t arow;
    if (FIRST) arow = (size_t)list_tok[grow0 + arl] * KTOT;
    else       arow = (size_t)(grow0 + arl) * KTOT;
    ag[i] = Abase + arow + k0 + sc;
    const int brl = wn * 64 + i * 16 + rl;   // row within the block's 128-col B tile
    bg[i] = Bbase + (size_t)e * NTOT * KTOT + (size_t)(n0 + brl) * KTOT + k0 + sc;
  }

  // --- fragment read offsets within the wave-private [64][32] tiles, swizzle folded in ---
  const int fr = lane & 15;
  const int q = lane >> 4;       // 16B chunk index within the 64B row
  int foff[4];
#pragma unroll
  for (int m = 0; m < 4; ++m) {
    const int row = m * 16 + fr;
    foff[m] = row * 32 + ((q ^ ((row >> 1) & 3)) * 8);
  }

  f32x4 acc[4][4] = {};

#define STAGE(S, SL)                                               \
  {                                                                \
    _Pragma("unroll")                                              \
    for (int i = 0; i < 4; ++i) {                                  \
      gld16(ag[i] + (S) * 32, &lds[wave][SL][0][i * 512]);         \
      gld16(bg[i] + (S) * 32, &lds[wave][SL][1][i * 512]);         \
    }                                                              \
  }

#define COMPUTE(SL)                                                   \
  {                                                                   \
    const unsigned short* A = &lds[wave][SL][0][0];                   \
    const unsigned short* B = &lds[wave][SL][1][0];                   \
    short8v af[4], bf[4];                                             \
    _Pragma("unroll")                                                 \
    for (int m = 0; m < 4; ++m) af[m] = *(const short8v*)&A[foff[m]]; \
    _Pragma("unroll")                                                 \
    for (int n = 0; n < 4; ++n) bf[n] = *(const short8v*)&B[foff[n]]; \
    __builtin_amdgcn_s_setprio(1);                                    \
    _Pragma("unroll")                                                 \
    for (int n = 0; n < 4; ++n)                                       \
      _Pragma("unroll")                                               \
      for (int m = 0; m < 4; ++m)                                     \
        acc[m][n] = __builtin_amdgcn_mfma_f32_16x16x32_bf16(af[m], bf[n], acc[m][n], 0, 0, 0); \
    __builtin_amdgcn_s_setprio(0);                                    \
  }

// wait: N batches (8 loads each) may remain outstanding; fence stops reordering
#define VMW(NSTR)                                                  \
  asm volatile("s_waitcnt vmcnt(" NSTR ")" ::: "memory");          \
  __builtin_amdgcn_sched_barrier(0);
// drain own ds_reads before re-staging a slot (free: reads already consumed by MFMAs)
#define LKW                                                        \
  asm volatile("s_waitcnt lgkmcnt(0)" ::: "memory");               \
  __builtin_amdgcn_sched_barrier(0);

  STAGE(0, 0);
  for (int s = 0; s < NT; s += 2) {
    if (s + 1 < NT) { STAGE(s + 1, 1); VMW("8") } else { VMW("0") }
    COMPUTE(0);
    if (s + 2 < NT) { LKW; STAGE(s + 2, 0); VMW("8") } else { VMW("0") }
    COMPUTE(1);
    LKW;
  }

#undef VMW
#undef LKW
#undef COMPUTE
#undef STAGE

  const int r4 = lane >> 4;
#pragma unroll
  for (int m = 0; m < 4; ++m) {
#pragma unroll
    for (int n = 0; n < 4; ++n) {
      const int gcol = n0 + wn * 64 + n * 16 + fr;
      float bv = 0.f;
      if (FIRST) bv = bias[e * NTOT + gcol];
#pragma unroll
      for (int r = 0; r < 4; ++r) {
        const int grow = grow0 + wm * 64 + m * 16 + r4 * 4 + r;
        float v = acc[m][n][r] + bv;
        if (FIRST) {
          v = 0.5f * v * (1.0f + erff(v * 0.70710678118654752f));
          ((unsigned short*)outp)[(size_t)grow * NTOT + gcol] = f2bf(v);
        } else {
          // bf16 partial (no bias; reduced in combine)
          ((unsigned short*)outp)[((size_t)ks * MAXROWS + grow) * NTOT + gcol] = f2bf(v);
        }
      }
    }
  }
}

// -------- combine: y[t] = w0*(sum_ks p16[ks][gs0]+b2[e0]) + w1*(...)  (4 bf16 slices) --------
template <int NSPLIT>
__global__ __launch_bounds__(256) void combine_kernel(const unsigned short* __restrict__ part,
                                                      const int* __restrict__ tok_gslot,
                                                      const int* __restrict__ tok_e,
                                                      const float* __restrict__ tok_w,
                                                      const float* __restrict__ b2,
                                                      float* __restrict__ y) {
  const int t = blockIdx.x;
  const int c = threadIdx.x * 4;
  const int gs0 = tok_gslot[t * 2 + 0], gs1 = tok_gslot[t * 2 + 1];
  const int e0 = tok_e[t * 2 + 0], e1 = tok_e[t * 2 + 1];
  const float w0 = tok_w[t * 2 + 0], w1 = tok_w[t * 2 + 1];
  float s0[4] = {0.f, 0.f, 0.f, 0.f}, s1[4] = {0.f, 0.f, 0.f, 0.f};
#pragma unroll
  for (int ks = 0; ks < NSPLIT; ++ks) {
    short4v p0 = *(const short4v*)&part[((size_t)ks * MAXROWS + gs0) * HID + c];
    short4v p1 = *(const short4v*)&part[((size_t)ks * MAXROWS + gs1) * HID + c];
#pragma unroll
    for (int i = 0; i < 4; ++i) {
      s0[i] += bf2f((unsigned short)p0[i]);
      s1[i] += bf2f((unsigned short)p1[i]);
    }
  }
  f32x4 bb0 = *(const f32x4*)&b2[e0 * HID + c];
  f32x4 bb1 = *(const f32x4*)&b2[e1 * HID + c];
  f32x4 r;
#pragma unroll
  for (int i = 0; i < 4; ++i)
    r[i] = w0 * (s0[i] + bb0[i]) + w1 * (s1[i] + bb1[i]);
  *(f32x4*)&y[(size_t)t * HID + c] = r;
}

extern "C" void kernel_launch(void* const* d_in, const int* in_sizes, int n_in,
                              void* d_out, int out_size, void* d_ws, size_t ws_size,
                              hipStream_t stream) {
  const float* x  = (const float*)d_in[0];
  const float* wg = (const float*)d_in[1];
  const float* W1 = (const float*)d_in[2];
  const float* b1 = (const float*)d_in[3];
  const float* W2 = (const float*)d_in[4];
  const float* b2 = (const float*)d_in[5];
  float* y = (float*)d_out;

  unsigned char* ws = (unsigned char*)d_ws;
  size_t off = 0;
  // w1t (live prep->gemm1) aliases part (bf16, 4 slices x 10.5MB = 42MB, live gemm2->combine)
  unsigned short* w1t  = (unsigned short*)(ws + off);
  unsigned short* part = (unsigned short*)(ws + off); off += (size_t)NE * HID * INTER * 2;  // 67MB
  unsigned short* w2t  = (unsigned short*)(ws + off); off += (size_t)NE * INTER * HID * 2;  // 67MB
  unsigned short* xb   = (unsigned short*)(ws + off); off += (size_t)NTOK * HID * 2;        // 4MB
  unsigned short* h    = (unsigned short*)(ws + off); off += (size_t)MAXROWS * INTER * 2;   // 42MB
  int* tok_e           = (int*)(ws + off);            off += NTOK * 2 * 4;
  float* tok_w         = (float*)(ws + off);          off += NTOK * 2 * 4;
  int* tok_gslot       = (int*)(ws + off);            off += NTOK * 2 * 4;
  int* list_tok        = (int*)(ws + off);            off += MAXROWS * 4;
  int* offs            = (int*)(ws + off);            off += 64;
  (void)ws_size; (void)in_sizes; (void)n_in; (void)out_size;

  // prep: convx (2048) + tconv1 (8192) + gating (2048) -- all independent
  prep_kernel<<<2048 + 8192 + 2048, 256, 0, stream>>>(x, W1, wg, xb, w1t, tok_e, tok_w);
  routing_kernel<<<1, 512, 0, stream>>>(tok_e, list_tok, tok_gslot, offs);
  // GEMM1 (1280 blocks) + tconv2 (8192 blocks) co-scheduled in one launch
  moe_gemm<HID, INTER, true, 1, 8192>
      <<<(INTER / 128) * (MAXROWS / 128) + 8192, 256, 0, stream>>>(
          xb, w1t, b1, list_tok, offs, (void*)h, W2, w2t);
  moe_gemm<INTER, HID, false, 4, 0>
      <<<(HID / 128) * (MAXROWS / 128) * 4, 256, 0, stream>>>(
          h, w2t, b2, list_tok, offs, (void*)part, nullptr, nullptr);
  combine_kernel<4><<<NTOK, 256, 0, stream>>>(part, tok_gslot, tok_e, tok_w, b2, y);
}

// Round 11
// 237.288 us; speedup vs baseline: 1.0910x; 1.0910x over previous
//
#include <hip/hip_runtime.h>
#include <hip/hip_bf16.h>

#define HID 1024
#define INTER 4096
#define NE 8
#define NTOK 2048
#define MAXROWS 6144   // 4096 pairs + 8*255 pad (256-aligned expert segments)

typedef __attribute__((ext_vector_type(8))) short short8v;
typedef __attribute__((ext_vector_type(4))) short short4v;
typedef __attribute__((ext_vector_type(4))) float f32x4;

__device__ __forceinline__ unsigned short f2bf(float f) {
  unsigned int u = __builtin_bit_cast(unsigned int, f);
  u = (u + 0x7FFFu + ((u >> 16) & 1u)) >> 16;
  return (unsigned short)u;
}
__device__ __forceinline__ float bf2f(unsigned short s) {
  unsigned int u = ((unsigned int)s) << 16;
  return __builtin_bit_cast(float, u);
}

typedef const __attribute__((address_space(1))) unsigned int* gas_t;
typedef __attribute__((address_space(3))) unsigned int* las_t;
__device__ __forceinline__ void gld16(const unsigned short* g, unsigned short* l) {
  __builtin_amdgcn_global_load_lds((gas_t)(const void*)g, (las_t)(void*)l, 16, 0, 0);
}

// ------- 256-thread 64x64 transpose tile (used by prep for W1) -------
__device__ __forceinline__ void tconv_tile(const float* __restrict__ in,
                                           unsigned short* __restrict__ out,
                                           int R, int C, int bx, int by, int z,
                                           float* __restrict__ t) {
  const int r0 = by * 64, c0 = bx * 64;
  const int tr = threadIdx.x / 16;
  const int tc = (threadIdx.x % 16) * 4;
  const float* ip = in + ((size_t)z * R + r0) * (size_t)C + c0;
#pragma unroll
  for (int p = 0; p < 4; ++p) {
    f32x4 v = *(const f32x4*)&ip[(size_t)(p * 16 + tr) * C + tc];
    t[(p * 16 + tr) * 65 + tc + 0] = v[0];
    t[(p * 16 + tr) * 65 + tc + 1] = v[1];
    t[(p * 16 + tr) * 65 + tc + 2] = v[2];
    t[(p * 16 + tr) * 65 + tc + 3] = v[3];
  }
  __syncthreads();
  unsigned short* op = out + ((size_t)z * C + c0) * (size_t)R + r0;
#pragma unroll
  for (int p = 0; p < 4; ++p) {
    int c = p * 16 + tr;
    unsigned int a0 = (unsigned int)f2bf(t[(tc + 0) * 65 + c]) |
                      ((unsigned int)f2bf(t[(tc + 1) * 65 + c]) << 16);
    unsigned int a1 = (unsigned int)f2bf(t[(tc + 2) * 65 + c]) |
                      ((unsigned int)f2bf(t[(tc + 3) * 65 + c]) << 16);
    uint2 val; val.x = a0; val.y = a1;
    *(uint2*)&op[(size_t)c * R + tc] = val;
  }
}

// ------- wave-private 64(i) x 32(h) transpose of W2 -> w2t (no barriers; 8 tiles/block) -------
__device__ __forceinline__ void wave_tconv2(const float* __restrict__ in,
                                            unsigned short* __restrict__ out,
                                            int gidx, float* __restrict__ sc, int lane) {
  const int e = gidx >> 11;                 // 2048 tiles per expert
  const int r = gidx & 2047;
  const int i0 = (r >> 5) * 64, h0 = (r & 31) * 32;
  const float* ip = in + ((size_t)e * INTER + i0) * HID + h0;
  f32x4 v[8];
#pragma unroll
  for (int p = 0; p < 8; ++p)
    v[p] = *(const f32x4*)&ip[(size_t)(p * 8 + (lane >> 3)) * HID + (lane & 7) * 4];
#pragma unroll
  for (int p = 0; p < 8; ++p) {
    const int row = p * 8 + (lane >> 3), col = (lane & 7) * 4;
#pragma unroll
    for (int j = 0; j < 4; ++j) sc[row * 37 + col + j] = v[p][j];
  }
  asm volatile("s_waitcnt lgkmcnt(0)" ::: "memory");
  __builtin_amdgcn_sched_barrier(0);
  unsigned short* op = out + ((size_t)e * HID + h0) * INTER + i0;
#pragma unroll
  for (int p = 0; p < 4; ++p) {
    const int c = p * 8 + (lane >> 3);
    const int r8 = (lane & 7) * 8;
    uint4 w;
    unsigned int* wp = (unsigned int*)&w;
#pragma unroll
    for (int j = 0; j < 4; ++j) {
      unsigned int lo = f2bf(sc[(r8 + 2 * j) * 37 + c]);
      unsigned int hi = f2bf(sc[(r8 + 2 * j + 1) * 37 + c]);
      wp[j] = lo | (hi << 16);
    }
    *(uint4*)&op[(size_t)c * INTER + r8] = w;
  }
}

// ---------------- prep: convx (2048 blocks) + tconv1 (8192) + gating (2048) ----------------
__global__ __launch_bounds__(256) void prep_kernel(const float* __restrict__ x,
                                                   const float* __restrict__ W1,
                                                   const float* __restrict__ wg,
                                                   unsigned short* __restrict__ xb,
                                                   unsigned short* __restrict__ w1t,
                                                   int* __restrict__ tok_e,
                                                   float* __restrict__ tok_w) {
  __shared__ float sh[64 * 65];
  int bid = blockIdx.x;
  if (bid < 2048) {   // convx
    size_t i = (size_t)bid * 256 + threadIdx.x;
    f32x4 v = *(const f32x4*)&x[i * 4];
    uint2 r;
    r.x = (unsigned int)f2bf(v[0]) | ((unsigned int)f2bf(v[1]) << 16);
    r.y = (unsigned int)f2bf(v[2]) | ((unsigned int)f2bf(v[3]) << 16);
    *(uint2*)&xb[i * 4] = r;
    return;
  }
  bid -= 2048;
  if (bid < 8192) {   // tconv1: W1 [E][H][I] -> w1t [E][I][H]
    tconv_tile(W1, w1t, HID, INTER, bid % 64, (bid / 64) % 16, bid / 1024, sh);
    return;
  }
  bid -= 8192;
  {   // gating
    const int t = bid;
    float acc[NE];
#pragma unroll
    for (int e = 0; e < NE; ++e) acc[e] = 0.f;
    for (int k = threadIdx.x; k < HID; k += 256) {
      float xv = x[(size_t)t * HID + k];
#pragma unroll
      for (int e = 0; e < NE; ++e) acc[e] += xv * wg[e * HID + k];
    }
#pragma unroll
    for (int e = 0; e < NE; ++e) {
#pragma unroll
      for (int off = 32; off >= 1; off >>= 1) acc[e] += __shfl_xor(acc[e], off, 64);
    }
    float* red = sh;
    const int wave = threadIdx.x >> 6, lane = threadIdx.x & 63;
    if (lane == 0) {
#pragma unroll
      for (int e = 0; e < NE; ++e) red[wave * NE + e] = acc[e];
    }
    __syncthreads();
    if (threadIdx.x == 0) {
      float l[NE];
#pragma unroll
      for (int e = 0; e < NE; ++e)
        l[e] = red[0 * NE + e] + red[1 * NE + e] + red[2 * NE + e] + red[3 * NE + e];
      int i0 = 0;
#pragma unroll
      for (int e = 1; e < NE; ++e) if (l[e] > l[i0]) i0 = e;
      int i1 = -1;
#pragma unroll
      for (int e = 0; e < NE; ++e) {
        if (e == i0) continue;
        if (i1 < 0 || l[e] > l[i1]) i1 = e;
      }
      float e1 = __expf(l[i1] - l[i0]);
      float w0 = 1.f / (1.f + e1);
      tok_e[t * 2 + 0] = i0;
      tok_e[t * 2 + 1] = i1;
      tok_w[t * 2 + 0] = w0;
      tok_w[t * 2 + 1] = 1.f - w0;
    }
  }
}

// ---------------- routing: per-expert compaction, segments padded to 256 ----------------
__global__ __launch_bounds__(512) void routing_kernel(const int* __restrict__ tok_e,
                                                      int* __restrict__ list_tok,
                                                      int* __restrict__ tok_gslot,
                                                      int* __restrict__ offs_out) {
  __shared__ int cnts[NE];
  __shared__ int offs_s[NE + 1];
  const int e = threadIdx.x >> 6, lane = threadIdx.x & 63;
  int c = 0;
  for (int base = 0; base < NTOK; base += 64) {
    int tok = base + lane;
    int e0 = tok_e[tok * 2], e1 = tok_e[tok * 2 + 1];
    bool m = (e0 == e) || (e1 == e);
    unsigned long long mask = __ballot(m);
    c += __popcll(mask);
  }
  if (lane == 0) cnts[e] = c;
  __syncthreads();
  if (threadIdx.x == 0) {
    int o = 0;
    for (int i = 0; i < NE; ++i) { offs_s[i] = o; o += (cnts[i] + 255) & ~255; }
    offs_s[NE] = o;
    for (int i = 0; i <= NE; ++i) offs_out[i] = offs_s[i];
  }
  __syncthreads();
  const int off = offs_s[e];
  int run = 0;
  for (int base = 0; base < NTOK; base += 64) {
    int tok = base + lane;
    int e0 = tok_e[tok * 2], e1 = tok_e[tok * 2 + 1];
    bool m = (e0 == e) || (e1 == e);
    unsigned long long mask = __ballot(m);
    int pos = run + __popcll(mask & ((1ull << lane) - 1ull));
    if (m) {
      int gs = off + pos;
      list_tok[gs] = tok;
      tok_gslot[tok * 2 + ((e0 == e) ? 0 : 1)] = gs;
    }
    run += __popcll(mask);
  }
  const int cnt = cnts[e];
  const int padded = (cnt + 255) & ~255;
  for (int p = cnt + lane; p < padded; p += 64) list_tok[off + p] = 0;
}

// ---- grouped GEMM: 256x256 tile, BK=64, 8 waves (wave 128x64), 8-phase-class schedule ----
// LDS per dbuf d: A[kh][256][32] + B[kh][256][32] bf16 (16KB blocks); 2 dbuf = 128KB.
// Per tile t (buf d): 4 phases (ks,mh): {8 ds_read_b128; stage 1 half-tile of t+1 into d^1
// (2 gld16); lgkmcnt(0)+fence; 16 MFMA}. vmcnt(4)+barrier ONLY at q1-end (guards this
// tile's k-half-1, staged one tile ago) and q3-end (guards next tile's k-half-0). Never 0
// in-loop. Chunk-XOR swizzle per 64B row (verified 0-conflict pattern from round 4),
// applied per k-half block (pre-swizzled global source + swizzled read chunk).
// TCONV: blocks past NWG run wave-private W2 transposes (fillers for scheduling holes).
template <int KTOT, int NTOT, bool FIRST, int NSPLIT, bool TCONV>
__global__ __launch_bounds__(512, 2) void moe_gemm(const unsigned short* __restrict__ Abase,
                                                   const unsigned short* __restrict__ Bbase,
                                                   const float* __restrict__ bias,
                                                   const int* __restrict__ list_tok,
                                                   const int* __restrict__ offs,
                                                   void* __restrict__ outp,
                                                   const float* __restrict__ W2f,
                                                   unsigned short* __restrict__ w2t) {
  constexpr int KS = KTOT / NSPLIT;   // K per slice
  constexpr int T = KS / 64;          // K-tiles (BK=64)
  constexpr int nM = MAXROWS / 256;   // 24
  constexpr int nN = NTOT / 256;
  constexpr int NWG = nM * nN * NSPLIT;
  __shared__ __align__(16) unsigned short lds[65536];   // 128 KB

  const int tid = threadIdx.x;
  const int wid = tid >> 6, lane = tid & 63;

  if (TCONV && (int)blockIdx.x >= NWG) {
    wave_tconv2(W2f, w2t, ((int)blockIdx.x - NWG) * 8 + wid,
                (float*)lds + wid * (64 * 37), lane);
    return;
  }

  int wg = blockIdx.x;
  wg = (wg & 7) * (NWG >> 3) + (wg >> 3);   // bijective XCD swizzle (NWG % 8 == 0)
  const int ksid = (NSPLIT > 1) ? (wg / (nM * nN)) : 0;
  const int rem = wg % (nM * nN);
  const int mt = rem % nM;                  // m fastest: neighbors share B panel in L2
  const int nt = rem / nM;
  const int grow0 = mt * 256;
  if (grow0 >= offs[NE]) return;
  int e = 0;
#pragma unroll
  for (int i = 1; i < NE; ++i) if (grow0 >= offs[i]) e = i;
  const int n0 = nt * 256;
  const int k0 = ksid * KS;

  // --- staging sources: call c covers rows c*128 + tid/4, chunk tid&3 (pre-XOR swizzled) ---
  const int jsrc = (((tid & 3) ^ ((tid >> 3) & 3)) * 8);   // shorts
  const unsigned short* ag[2];
  const unsigned short* bg[2];
#pragma unroll
  for (int c = 0; c < 2; ++c) {
    const int R = c * 128 + (tid >> 2);
    size_t arow;
    if (FIRST) arow = (size_t)list_tok[grow0 + R] * KTOT;
    else       arow = (size_t)(grow0 + R) * KTOT;
    ag[c] = Abase + arow + k0 + jsrc;
    bg[c] = Bbase + (size_t)e * NTOT * KTOT + (size_t)(n0 + R) * KTOT + k0 + jsrc;
  }

  // --- fragment read offsets (shorts, within a kh block), swizzle folded in ---
  const int fr = lane & 15, q4 = lane >> 4;
  const int csw = (q4 ^ ((fr >> 1) & 3)) * 8;
  const int wm = wid >> 2, wn = wid & 3;    // wave tile: rows wm*128+[0,128), cols wn*64+[0,64)
  int aoff[4], boff[4];
#pragma unroll
  for (int m = 0; m < 4; ++m) aoff[m] = (wm * 128 + m * 16 + fr) * 32 + csw;
#pragma unroll
  for (int n = 0; n < 4; ++n) boff[n] = 16384 + (wn * 64 + n * 16 + fr) * 32 + csw;

  f32x4 acc[8][4] = {};

#define STG(MAT, KH, D1, TOFF)                                                          \
  {                                                                                     \
    const unsigned short* s0 = ((MAT) ? bg[0] : ag[0]) + (TOFF) + (KH) * 32;            \
    const unsigned short* s1 = ((MAT) ? bg[1] : ag[1]) + (TOFF) + (KH) * 32;            \
    unsigned short* db = lds + (D1) * 32768 + (MAT) * 16384 + (KH) * 8192 + wid * 512;  \
    gld16(s0, db);                                                                      \
    gld16(s1, db + 4096);                                                               \
  }

#define PH(DD, KSS, MH, DOSTG, SMAT, SKH, TOFF)                                         \
  {                                                                                     \
    const unsigned short* Lp = lds + (DD) * 32768 + (KSS) * 8192;                       \
    short8v af[4], bf[4];                                                               \
    _Pragma("unroll")                                                                   \
    for (int m = 0; m < 4; ++m) af[m] = *(const short8v*)&Lp[(MH) * 2048 + aoff[m]];    \
    _Pragma("unroll")                                                                   \
    for (int n = 0; n < 4; ++n) bf[n] = *(const short8v*)&Lp[boff[n]];                  \
    if (DOSTG) STG(SMAT, SKH, (DD) ^ 1, TOFF);                                          \
    asm volatile("s_waitcnt lgkmcnt(0)" ::: "memory");                                  \
    __builtin_amdgcn_sched_barrier(0);                                                  \
    __builtin_amdgcn_s_setprio(1);                                                      \
    _Pragma("unroll")                                                                   \
    for (int n = 0; n < 4; ++n)                                                         \
      _Pragma("unroll")                                                                 \
      for (int m = 0; m < 4; ++m)                                                       \
        acc[(MH) * 4 + m][n] = __builtin_amdgcn_mfma_f32_16x16x32_bf16(                 \
            af[m], bf[n], acc[(MH) * 4 + m][n], 0, 0, 0);                               \
    __builtin_amdgcn_s_setprio(0);                                                      \
  }

  // prologue: stage tile 0 fully into buf 0; A_k0/B_k0 must land, A_k1/B_k1 may float
  STG(0, 0, 0, 0); STG(1, 0, 0, 0); STG(0, 1, 0, 0); STG(1, 1, 0, 0);
  asm volatile("s_waitcnt vmcnt(4)" ::: "memory");
  asm volatile("s_barrier" ::: "memory");

  for (int t = 0; t < T; ++t) {
    const int d = t & 1;
    const int toff = (t + 1) * 64;
    const bool hn = (t + 1 < T);
    PH(d, 0, 0, hn, 0, 0, toff);       // reads (ks0, mh0); stage A_k0(t+1)
    PH(d, 0, 1, hn, 1, 0, toff);       // reads (ks0, mh1); stage B_k0(t+1)
    if (hn) asm volatile("s_waitcnt vmcnt(4)" ::: "memory");
    else    asm volatile("s_waitcnt vmcnt(0)" ::: "memory");
    asm volatile("s_barrier" ::: "memory");   // A_k1/B_k1(t) now valid block-wide
    PH(d, 1, 0, hn, 0, 1, toff);       // reads (ks1, mh0); stage A_k1(t+1)
    PH(d, 1, 1, hn, 1, 1, toff);       // reads (ks1, mh1); stage B_k1(t+1)
    if (hn) {
      asm volatile("s_waitcnt vmcnt(4)" ::: "memory");
      asm volatile("s_barrier" ::: "memory"); // A_k0/B_k0(t+1) now valid block-wide
    }
  }

#undef PH
#undef STG

  // epilogue: C/D map col=lane&15, row=(lane>>4)*4+reg
#pragma unroll
  for (int m = 0; m < 8; ++m) {
#pragma unroll
    for (int n = 0; n < 4; ++n) {
      const int gcol = n0 + wn * 64 + n * 16 + fr;
      float bv = 0.f;
      if (FIRST) bv = bias[e * NTOT + gcol];
#pragma unroll
      for (int r = 0; r < 4; ++r) {
        const int grow = grow0 + wm * 128 + m * 16 + q4 * 4 + r;
        float v = acc[m][n][r] + bv;
        if (FIRST) {
          v = 0.5f * v * (1.0f + erff(v * 0.70710678118654752f));
          ((unsigned short*)outp)[(size_t)grow * NTOT + gcol] = f2bf(v);
        } else {
          ((unsigned short*)outp)[((size_t)ksid * MAXROWS + grow) * NTOT + gcol] = f2bf(v);
        }
      }
    }
  }
}

// -------- combine: y[t] = w0*(sum_ks p16[ks][gs0]+b2[e0]) + w1*(...)  (NSPLIT bf16 slices) ----
template <int NSPLIT>
__global__ __launch_bounds__(256) void combine_kernel(const unsigned short* __restrict__ part,
                                                      const int* __restrict__ tok_gslot,
                                                      const int* __restrict__ tok_e,
                                                      const float* __restrict__ tok_w,
                                                      const float* __restrict__ b2,
                                                      float* __restrict__ y) {
  const int t = blockIdx.x;
  const int c = threadIdx.x * 4;
  const int gs0 = tok_gslot[t * 2 + 0], gs1 = tok_gslot[t * 2 + 1];
  const int e0 = tok_e[t * 2 + 0], e1 = tok_e[t * 2 + 1];
  const float w0 = tok_w[t * 2 + 0], w1 = tok_w[t * 2 + 1];
  float s0[4] = {0.f, 0.f, 0.f, 0.f}, s1[4] = {0.f, 0.f, 0.f, 0.f};
#pragma unroll
  for (int ks = 0; ks < NSPLIT; ++ks) {
    short4v p0 = *(const short4v*)&part[((size_t)ks * MAXROWS + gs0) * HID + c];
    short4v p1 = *(const short4v*)&part[((size_t)ks * MAXROWS + gs1) * HID + c];
#pragma unroll
    for (int i = 0; i < 4; ++i) {
      s0[i] += bf2f((unsigned short)p0[i]);
      s1[i] += bf2f((unsigned short)p1[i]);
    }
  }
  f32x4 bb0 = *(const f32x4*)&b2[e0 * HID + c];
  f32x4 bb1 = *(const f32x4*)&b2[e1 * HID + c];
  f32x4 r;
#pragma unroll
  for (int i = 0; i < 4; ++i)
    r[i] = w0 * (s0[i] + bb0[i]) + w1 * (s1[i] + bb1[i]);
  *(f32x4*)&y[(size_t)t * HID + c] = r;
}

extern "C" void kernel_launch(void* const* d_in, const int* in_sizes, int n_in,
                              void* d_out, int out_size, void* d_ws, size_t ws_size,
                              hipStream_t stream) {
  const float* x  = (const float*)d_in[0];
  const float* wg = (const float*)d_in[1];
  const float* W1 = (const float*)d_in[2];
  const float* b1 = (const float*)d_in[3];
  const float* W2 = (const float*)d_in[4];
  const float* b2 = (const float*)d_in[5];
  float* y = (float*)d_out;

  unsigned char* ws = (unsigned char*)d_ws;
  size_t off = 0;
  // region1: w1t (67MB, live prep->gemm1) aliases part (8 bf16 slices = 100.7MB, gemm2->combine)
  unsigned short* w1t  = (unsigned short*)(ws + off);
  unsigned short* part = (unsigned short*)(ws + off);
  off += (size_t)8 * MAXROWS * HID * 2;                                    // 100.7MB
  unsigned short* w2t  = (unsigned short*)(ws + off); off += (size_t)NE * HID * INTER * 2;  // 67MB
  unsigned short* xb   = (unsigned short*)(ws + off); off += (size_t)NTOK * HID * 2;        // 4MB
  unsigned short* h    = (unsigned short*)(ws + off); off += (size_t)MAXROWS * INTER * 2;   // 50MB
  int* tok_e           = (int*)(ws + off);            off += NTOK * 2 * 4;
  float* tok_w         = (float*)(ws + off);          off += NTOK * 2 * 4;
  int* tok_gslot       = (int*)(ws + off);            off += NTOK * 2 * 4;
  int* list_tok        = (int*)(ws + off);            off += MAXROWS * 4;
  int* offs            = (int*)(ws + off);            off += 64;
  (void)ws_size; (void)in_sizes; (void)n_in; (void)out_size;

  // prep: convx (2048) + tconv1 (8192) + gating (2048)
  prep_kernel<<<2048 + 8192 + 2048, 256, 0, stream>>>(x, W1, wg, xb, w1t, tok_e, tok_w);
  routing_kernel<<<1, 512, 0, stream>>>(tok_e, list_tok, tok_gslot, offs);
  // GEMM1 (384 blocks, 256x256) + 2048 wave-tconv2 filler blocks, 512 threads
  moe_gemm<HID, INTER, true, 1, true>
      <<<(MAXROWS / 256) * (INTER / 256) + 2048, 512, 0, stream>>>(
          xb, w1t, b1, list_tok, offs, (void*)h, W2, w2t);
  // GEMM2: splitK=8 -> 768 blocks (3 full rounds at 1 block/CU)
  moe_gemm<INTER, HID, false, 8, false>
      <<<(MAXROWS / 256) * (HID / 256) * 8, 512, 0, stream>>>(
          h, w2t, b2, list_tok, offs, (void*)part, nullptr, nullptr);
  combine_kernel<8><<<NTOK, 256, 0, stream>>>(part, tok_gslot, tok_e, tok_w, b2, y);
}

// Round 12
// 225.328 us; speedup vs baseline: 1.1489x; 1.0531x over previous
//
#include <hip/hip_runtime.h>
#include <hip/hip_bf16.h>

#define HID 1024
#define INTER 4096
#define NE 8
#define NTOK 2048
#define MAXROWS 6144   // 4096 pairs + 8*255 pad (256-aligned expert segments)

typedef __attribute__((ext_vector_type(8))) short short8v;
typedef __attribute__((ext_vector_type(4))) short short4v;
typedef __attribute__((ext_vector_type(4))) float f32x4;

__device__ __forceinline__ unsigned short f2bf(float f) {
  unsigned int u = __builtin_bit_cast(unsigned int, f);
  u = (u + 0x7FFFu + ((u >> 16) & 1u)) >> 16;
  return (unsigned short)u;
}
__device__ __forceinline__ float bf2f(unsigned short s) {
  unsigned int u = ((unsigned int)s) << 16;
  return __builtin_bit_cast(float, u);
}

typedef const __attribute__((address_space(1))) unsigned int* gas_t;
typedef __attribute__((address_space(3))) unsigned int* las_t;
__device__ __forceinline__ void gld16(const unsigned short* g, unsigned short* l) {
  __builtin_amdgcn_global_load_lds((gas_t)(const void*)g, (las_t)(void*)l, 16, 0, 0);
}

// ------- 256-thread 64x64 transpose tile (used by prep for W1) -------
__device__ __forceinline__ void tconv_tile(const float* __restrict__ in,
                                           unsigned short* __restrict__ out,
                                           int R, int C, int bx, int by, int z,
                                           float* __restrict__ t) {
  const int r0 = by * 64, c0 = bx * 64;
  const int tr = threadIdx.x / 16;
  const int tc = (threadIdx.x % 16) * 4;
  const float* ip = in + ((size_t)z * R + r0) * (size_t)C + c0;
#pragma unroll
  for (int p = 0; p < 4; ++p) {
    f32x4 v = *(const f32x4*)&ip[(size_t)(p * 16 + tr) * C + tc];
    t[(p * 16 + tr) * 65 + tc + 0] = v[0];
    t[(p * 16 + tr) * 65 + tc + 1] = v[1];
    t[(p * 16 + tr) * 65 + tc + 2] = v[2];
    t[(p * 16 + tr) * 65 + tc + 3] = v[3];
  }
  __syncthreads();
  unsigned short* op = out + ((size_t)z * C + c0) * (size_t)R + r0;
#pragma unroll
  for (int p = 0; p < 4; ++p) {
    int c = p * 16 + tr;
    unsigned int a0 = (unsigned int)f2bf(t[(tc + 0) * 65 + c]) |
                      ((unsigned int)f2bf(t[(tc + 1) * 65 + c]) << 16);
    unsigned int a1 = (unsigned int)f2bf(t[(tc + 2) * 65 + c]) |
                      ((unsigned int)f2bf(t[(tc + 3) * 65 + c]) << 16);
    uint2 val; val.x = a0; val.y = a1;
    *(uint2*)&op[(size_t)c * R + tc] = val;
  }
}

// ------- wave-private 64(i) x 32(h) transpose of W2 -> w2t (no barriers; 8 tiles/block) -------
__device__ __forceinline__ void wave_tconv2(const float* __restrict__ in,
                                            unsigned short* __restrict__ out,
                                            int gidx, float* __restrict__ sc, int lane) {
  const int e = gidx >> 11;                 // 2048 tiles per expert
  const int r = gidx & 2047;
  const int i0 = (r >> 5) * 64, h0 = (r & 31) * 32;
  const float* ip = in + ((size_t)e * INTER + i0) * HID + h0;
  f32x4 v[8];
#pragma unroll
  for (int p = 0; p < 8; ++p)
    v[p] = *(const f32x4*)&ip[(size_t)(p * 8 + (lane >> 3)) * HID + (lane & 7) * 4];
#pragma unroll
  for (int p = 0; p < 8; ++p) {
    const int row = p * 8 + (lane >> 3), col = (lane & 7) * 4;
#pragma unroll
    for (int j = 0; j < 4; ++j) sc[row * 37 + col + j] = v[p][j];
  }
  asm volatile("s_waitcnt lgkmcnt(0)" ::: "memory");
  __builtin_amdgcn_sched_barrier(0);
  unsigned short* op = out + ((size_t)e * HID + h0) * INTER + i0;
#pragma unroll
  for (int p = 0; p < 4; ++p) {
    const int c = p * 8 + (lane >> 3);
    const int r8 = (lane & 7) * 8;
    uint4 w;
    unsigned int* wp = (unsigned int*)&w;
#pragma unroll
    for (int j = 0; j < 4; ++j) {
      unsigned int lo = f2bf(sc[(r8 + 2 * j) * 37 + c]);
      unsigned int hi = f2bf(sc[(r8 + 2 * j + 1) * 37 + c]);
      wp[j] = lo | (hi << 16);
    }
    *(uint4*)&op[(size_t)c * INTER + r8] = w;
  }
}

// ---------------- prep: convx (2048 blocks) + tconv1 (8192) + gating (2048) ----------------
__global__ __launch_bounds__(256) void prep_kernel(const float* __restrict__ x,
                                                   const float* __restrict__ W1,
                                                   const float* __restrict__ wg,
                                                   unsigned short* __restrict__ xb,
                                                   unsigned short* __restrict__ w1t,
                                                   int* __restrict__ tok_e,
                                                   float* __restrict__ tok_w) {
  __shared__ float sh[64 * 65];
  int bid = blockIdx.x;
  if (bid < 2048) {   // convx
    size_t i = (size_t)bid * 256 + threadIdx.x;
    f32x4 v = *(const f32x4*)&x[i * 4];
    uint2 r;
    r.x = (unsigned int)f2bf(v[0]) | ((unsigned int)f2bf(v[1]) << 16);
    r.y = (unsigned int)f2bf(v[2]) | ((unsigned int)f2bf(v[3]) << 16);
    *(uint2*)&xb[i * 4] = r;
    return;
  }
  bid -= 2048;
  if (bid < 8192) {   // tconv1: W1 [E][H][I] -> w1t [E][I][H]
    tconv_tile(W1, w1t, HID, INTER, bid % 64, (bid / 64) % 16, bid / 1024, sh);
    return;
  }
  bid -= 8192;
  {   // gating
    const int t = bid;
    float acc[NE];
#pragma unroll
    for (int e = 0; e < NE; ++e) acc[e] = 0.f;
    for (int k = threadIdx.x; k < HID; k += 256) {
      float xv = x[(size_t)t * HID + k];
#pragma unroll
      for (int e = 0; e < NE; ++e) acc[e] += xv * wg[e * HID + k];
    }
#pragma unroll
    for (int e = 0; e < NE; ++e) {
#pragma unroll
      for (int off = 32; off >= 1; off >>= 1) acc[e] += __shfl_xor(acc[e], off, 64);
    }
    float* red = sh;
    const int wave = threadIdx.x >> 6, lane = threadIdx.x & 63;
    if (lane == 0) {
#pragma unroll
      for (int e = 0; e < NE; ++e) red[wave * NE + e] = acc[e];
    }
    __syncthreads();
    if (threadIdx.x == 0) {
      float l[NE];
#pragma unroll
      for (int e = 0; e < NE; ++e)
        l[e] = red[0 * NE + e] + red[1 * NE + e] + red[2 * NE + e] + red[3 * NE + e];
      int i0 = 0;
#pragma unroll
      for (int e = 1; e < NE; ++e) if (l[e] > l[i0]) i0 = e;
      int i1 = -1;
#pragma unroll
      for (int e = 0; e < NE; ++e) {
        if (e == i0) continue;
        if (i1 < 0 || l[e] > l[i1]) i1 = e;
      }
      float e1 = __expf(l[i1] - l[i0]);
      float w0 = 1.f / (1.f + e1);
      tok_e[t * 2 + 0] = i0;
      tok_e[t * 2 + 1] = i1;
      tok_w[t * 2 + 0] = w0;
      tok_w[t * 2 + 1] = 1.f - w0;
    }
  }
}

// ---------------- routing: per-expert compaction, segments padded to 256 ----------------
__global__ __launch_bounds__(512) void routing_kernel(const int* __restrict__ tok_e,
                                                      int* __restrict__ list_tok,
                                                      int* __restrict__ tok_gslot,
                                                      int* __restrict__ offs_out) {
  __shared__ int cnts[NE];
  __shared__ int offs_s[NE + 1];
  const int e = threadIdx.x >> 6, lane = threadIdx.x & 63;
  int c = 0;
  for (int base = 0; base < NTOK; base += 64) {
    int tok = base + lane;
    int e0 = tok_e[tok * 2], e1 = tok_e[tok * 2 + 1];
    bool m = (e0 == e) || (e1 == e);
    unsigned long long mask = __ballot(m);
    c += __popcll(mask);
  }
  if (lane == 0) cnts[e] = c;
  __syncthreads();
  if (threadIdx.x == 0) {
    int o = 0;
    for (int i = 0; i < NE; ++i) { offs_s[i] = o; o += (cnts[i] + 255) & ~255; }
    offs_s[NE] = o;
    for (int i = 0; i <= NE; ++i) offs_out[i] = offs_s[i];
  }
  __syncthreads();
  const int off = offs_s[e];
  int run = 0;
  for (int base = 0; base < NTOK; base += 64) {
    int tok = base + lane;
    int e0 = tok_e[tok * 2], e1 = tok_e[tok * 2 + 1];
    bool m = (e0 == e) || (e1 == e);
    unsigned long long mask = __ballot(m);
    int pos = run + __popcll(mask & ((1ull << lane) - 1ull));
    if (m) {
      int gs = off + pos;
      list_tok[gs] = tok;
      tok_gslot[tok * 2 + ((e0 == e) ? 0 : 1)] = gs;
    }
    run += __popcll(mask);
  }
  const int cnt = cnts[e];
  const int padded = (cnt + 255) & ~255;
  for (int p = cnt + lane; p < padded; p += 64) list_tok[off + p] = 0;
}

// ---- grouped GEMM: 256x256 tile, BK=64, 8 waves (wave 128x64), MINIMUM 2-PHASE loop ----
// Catalog T3 recipe, literally: STAGE(buf^1, t+1); ds_read frags; lgkmcnt(0); MFMA;
// vmcnt(0)+barrier ONCE per K-tile. LDS: 2 dbuf x (A[256][64]+B[256][64]) bf16 = 128KB.
// Swizzle: 16B chunk c of a 128B row stored at c ^ (row&7); involution; kk=1 read offset
// = kk=0 offset ^ 32 shorts. Lanes of a quarter-wave hit 8 distinct chunk columns -> 2-way
// (free). Hazards: buf reads lgkm-drained in-tile; re-stage of a buf is after the NEXT
// tile's end barrier; vmcnt(0)+barrier at tile end publishes staging block-wide.
// TCONV: blocks past NWG run wave-private W2 transposes (fillers).
template <int KTOT, int NTOT, bool FIRST, int NSPLIT, bool TCONV>
__global__ __launch_bounds__(512, 2) void moe_gemm(const unsigned short* __restrict__ Abase,
                                                   const unsigned short* __restrict__ Bbase,
                                                   const float* __restrict__ bias,
                                                   const int* __restrict__ list_tok,
                                                   const int* __restrict__ offs,
                                                   void* __restrict__ outp,
                                                   const float* __restrict__ W2f,
                                                   unsigned short* __restrict__ w2t) {
  constexpr int KS = KTOT / NSPLIT;   // K per slice
  constexpr int T = KS / 64;          // K-tiles (BK=64)
  constexpr int nM = MAXROWS / 256;   // 24
  constexpr int nN = NTOT / 256;
  constexpr int NWG = nM * nN * NSPLIT;
  __shared__ __align__(16) unsigned short lds[65536];   // 128 KB

  const int tid = threadIdx.x;
  const int wid = tid >> 6, lane = tid & 63;

  if (TCONV && (int)blockIdx.x >= NWG) {
    wave_tconv2(W2f, w2t, ((int)blockIdx.x - NWG) * 8 + wid,
                (float*)lds + wid * (64 * 37), lane);
    return;
  }

  int wg = blockIdx.x;
  wg = (wg & 7) * (NWG >> 3) + (wg >> 3);   // bijective XCD swizzle (NWG % 8 == 0)
  const int ksid = (NSPLIT > 1) ? (wg / (nM * nN)) : 0;
  const int rem = wg % (nM * nN);
  const int mt = rem % nM;                  // m fastest: neighbors share B panel in L2
  const int nt = rem / nM;
  const int grow0 = mt * 256;
  if (grow0 >= offs[NE]) return;
  int e = 0;
#pragma unroll
  for (int i = 1; i < NE; ++i) if (grow0 >= offs[i]) e = i;
  const int n0 = nt * 256;
  const int k0 = ksid * KS;

  // --- staging sources: call c covers row c*64 + tid/8, chunk tid&7 (pre-XOR swizzled).
  // Lanes 8j..8j+7 cover one full 128B row (chunks permuted) -> coalesced.
  const int srow8 = tid >> 3;                               // 0..63
  const int jsw = ((tid & 7) ^ (srow8 & 7)) * 8;            // swizzled chunk, shorts
  const unsigned short* ag[4];
  const unsigned short* bg[4];
#pragma unroll
  for (int c = 0; c < 4; ++c) {
    const int R = c * 64 + srow8;
    size_t arow;
    if (FIRST) arow = (size_t)list_tok[grow0 + R] * KTOT;
    else       arow = (size_t)(grow0 + R) * KTOT;
    ag[c] = Abase + arow + k0 + jsw;
    bg[c] = Bbase + (size_t)e * NTOT * KTOT + (size_t)(n0 + R) * KTOT + k0 + jsw;
  }

  // --- fragment read offsets for kk=0 (shorts), swizzle folded; kk=1 = ^32 ---
  const int fr = lane & 15, q4 = lane >> 4;
  const int wm = wid >> 2, wn = wid & 3;    // wave tile: rows wm*128+[0,128), cols wn*64+[0,64)
  int aoff[8], boff[4];
#pragma unroll
  for (int m = 0; m < 8; ++m) {
    const int row = wm * 128 + m * 16 + fr;
    aoff[m] = row * 64 + ((q4 ^ (row & 7)) * 8);
  }
#pragma unroll
  for (int n = 0; n < 4; ++n) {
    const int row = wn * 64 + n * 16 + fr;
    boff[n] = row * 64 + ((q4 ^ (row & 7)) * 8);
  }

  f32x4 acc[8][4] = {};

// stage K-tile TT into dbuf D: 8 gld16 (dest base wave-uniform; lane offset = lane*16B)
#define STAGE(TT, D)                                                         \
  {                                                                          \
    _Pragma("unroll")                                                        \
    for (int c = 0; c < 4; ++c) {                                            \
      gld16(ag[c] + (TT) * 64, lds + (D) * 32768 + (c * 64 + wid * 8) * 64); \
      gld16(bg[c] + (TT) * 64,                                               \
            lds + (D) * 32768 + 16384 + (c * 64 + wid * 8) * 64);            \
    }                                                                        \
  }

#define KKC(D, KK)                                                             \
  {                                                                            \
    const unsigned short* La = lds + (D) * 32768;                              \
    const unsigned short* Lb = La + 16384;                                     \
    short8v af[8], bf[4];                                                      \
    _Pragma("unroll")                                                          \
    for (int m = 0; m < 8; ++m) af[m] = *(const short8v*)&La[aoff[m] ^ ((KK) * 32)]; \
    _Pragma("unroll")                                                          \
    for (int n = 0; n < 4; ++n) bf[n] = *(const short8v*)&Lb[boff[n] ^ ((KK) * 32)]; \
    asm volatile("s_waitcnt lgkmcnt(0)" ::: "memory");                         \
    __builtin_amdgcn_sched_barrier(0);                                         \
    __builtin_amdgcn_s_setprio(1);                                             \
    _Pragma("unroll")                                                          \
    for (int n = 0; n < 4; ++n)                                                \
      _Pragma("unroll")                                                        \
      for (int m = 0; m < 8; ++m)                                              \
        acc[m][n] = __builtin_amdgcn_mfma_f32_16x16x32_bf16(af[m], bf[n], acc[m][n], 0, 0, 0); \
    __builtin_amdgcn_s_setprio(0);                                             \
  }

  // prologue
  STAGE(0, 0);
  asm volatile("s_waitcnt vmcnt(0)" ::: "memory");
  asm volatile("s_barrier" ::: "memory");

  for (int t = 0; t < T; ++t) {
    const int d = t & 1;
    if (t + 1 < T) STAGE(t + 1, d ^ 1);
    KKC(d, 0);
    KKC(d, 1);
    if (t + 1 < T) {
      asm volatile("s_waitcnt vmcnt(0)" ::: "memory");
      asm volatile("s_barrier" ::: "memory");
    }
  }

#undef KKC
#undef STAGE

  // epilogue: C/D map col=lane&15, row=(lane>>4)*4+reg
#pragma unroll
  for (int m = 0; m < 8; ++m) {
#pragma unroll
    for (int n = 0; n < 4; ++n) {
      const int gcol = n0 + wn * 64 + n * 16 + fr;
      float bv = 0.f;
      if (FIRST) bv = bias[e * NTOT + gcol];
#pragma unroll
      for (int r = 0; r < 4; ++r) {
        const int grow = grow0 + wm * 128 + m * 16 + q4 * 4 + r;
        float v = acc[m][n][r] + bv;
        if (FIRST) {
          v = 0.5f * v * (1.0f + erff(v * 0.70710678118654752f));
          ((unsigned short*)outp)[(size_t)grow * NTOT + gcol] = f2bf(v);
        } else {
          ((unsigned short*)outp)[((size_t)ksid * MAXROWS + grow) * NTOT + gcol] = f2bf(v);
        }
      }
    }
  }
}

// -------- combine: y[t] = w0*(sum_ks p16[ks][gs0]+b2[e0]) + w1*(...)  (NSPLIT bf16 slices) ----
template <int NSPLIT>
__global__ __launch_bounds__(256) void combine_kernel(const unsigned short* __restrict__ part,
                                                      const int* __restrict__ tok_gslot,
                                                      const int* __restrict__ tok_e,
                                                      const float* __restrict__ tok_w,
                                                      const float* __restrict__ b2,
                                                      float* __restrict__ y) {
  const int t = blockIdx.x;
  const int c = threadIdx.x * 4;
  const int gs0 = tok_gslot[t * 2 + 0], gs1 = tok_gslot[t * 2 + 1];
  const int e0 = tok_e[t * 2 + 0], e1 = tok_e[t * 2 + 1];
  const float w0 = tok_w[t * 2 + 0], w1 = tok_w[t * 2 + 1];
  float s0[4] = {0.f, 0.f, 0.f, 0.f}, s1[4] = {0.f, 0.f, 0.f, 0.f};
#pragma unroll
  for (int ks = 0; ks < NSPLIT; ++ks) {
    short4v p0 = *(const short4v*)&part[((size_t)ks * MAXROWS + gs0) * HID + c];
    short4v p1 = *(const short4v*)&part[((size_t)ks * MAXROWS + gs1) * HID + c];
#pragma unroll
    for (int i = 0; i < 4; ++i) {
      s0[i] += bf2f((unsigned short)p0[i]);
      s1[i] += bf2f((unsigned short)p1[i]);
    }
  }
  f32x4 bb0 = *(const f32x4*)&b2[e0 * HID + c];
  f32x4 bb1 = *(const f32x4*)&b2[e1 * HID + c];
  f32x4 r;
#pragma unroll
  for (int i = 0; i < 4; ++i)
    r[i] = w0 * (s0[i] + bb0[i]) + w1 * (s1[i] + bb1[i]);
  *(f32x4*)&y[(size_t)t * HID + c] = r;
}

extern "C" void kernel_launch(void* const* d_in, const int* in_sizes, int n_in,
                              void* d_out, int out_size, void* d_ws, size_t ws_size,
                              hipStream_t stream) {
  const float* x  = (const float*)d_in[0];
  const float* wg = (const float*)d_in[1];
  const float* W1 = (const float*)d_in[2];
  const float* b1 = (const float*)d_in[3];
  const float* W2 = (const float*)d_in[4];
  const float* b2 = (const float*)d_in[5];
  float* y = (float*)d_out;

  unsigned char* ws = (unsigned char*)d_ws;
  size_t off = 0;
  // region1: w1t (67MB, live prep->gemm1) aliases part (8 bf16 slices = 100.7MB, gemm2->combine)
  unsigned short* w1t  = (unsigned short*)(ws + off);
  unsigned short* part = (unsigned short*)(ws + off);
  off += (size_t)8 * MAXROWS * HID * 2;                                    // 100.7MB
  unsigned short* w2t  = (unsigned short*)(ws + off); off += (size_t)NE * HID * INTER * 2;  // 67MB
  unsigned short* xb   = (unsigned short*)(ws + off); off += (size_t)NTOK * HID * 2;        // 4MB
  unsigned short* h    = (unsigned short*)(ws + off); off += (size_t)MAXROWS * INTER * 2;   // 50MB
  int* tok_e           = (int*)(ws + off);            off += NTOK * 2 * 4;
  float* tok_w         = (float*)(ws + off);          off += NTOK * 2 * 4;
  int* tok_gslot       = (int*)(ws + off);            off += NTOK * 2 * 4;
  int* list_tok        = (int*)(ws + off);            off += MAXROWS * 4;
  int* offs            = (int*)(ws + off);            off += 64;
  (void)ws_size; (void)in_sizes; (void)n_in; (void)out_size;

  // prep: convx (2048) + tconv1 (8192) + gating (2048)
  prep_kernel<<<2048 + 8192 + 2048, 256, 0, stream>>>(x, W1, wg, xb, w1t, tok_e, tok_w);
  routing_kernel<<<1, 512, 0, stream>>>(tok_e, list_tok, tok_gslot, offs);
  // GEMM1 (384 blocks, 256x256) + 2048 wave-tconv2 filler blocks, 512 threads
  moe_gemm<HID, INTER, true, 1, true>
      <<<(MAXROWS / 256) * (INTER / 256) + 2048, 512, 0, stream>>>(
          xb, w1t, b1, list_tok, offs, (void*)h, W2, w2t);
  // GEMM2: splitK=8 -> 768 blocks (3 exact rounds at 1 block/CU)
  moe_gemm<INTER, HID, false, 8, false>
      <<<(MAXROWS / 256) * (HID / 256) * 8, 512, 0, stream>>>(
          h, w2t, b2, list_tok, offs, (void*)part, nullptr, nullptr);
  combine_kernel<8><<<NTOK, 256, 0, stream>>>(part, tok_gslot, tok_e, tok_w, b2, y);
}

// Round 13
// 215.374 us; speedup vs baseline: 1.2021x; 1.0462x over previous
//
#include <hip/hip_runtime.h>
#include <hip/hip_bf16.h>

#define HID 1024
#define INTER 4096
#define NE 8
#define NTOK 2048
#define MAXROWS 5120   // 4096 pairs + 8*127 pad, rounded up

typedef __attribute__((ext_vector_type(8))) short short8v;
typedef __attribute__((ext_vector_type(4))) short short4v;
typedef __attribute__((ext_vector_type(4))) float f32x4;

__device__ __forceinline__ unsigned short f2bf(float f) {
  unsigned int u = __builtin_bit_cast(unsigned int, f);
  u = (u + 0x7FFFu + ((u >> 16) & 1u)) >> 16;
  return (unsigned short)u;
}
__device__ __forceinline__ float bf2f(unsigned short s) {
  unsigned int u = ((unsigned int)s) << 16;
  return __builtin_bit_cast(float, u);
}

typedef const __attribute__((address_space(1))) unsigned int* gas_t;
typedef __attribute__((address_space(3))) unsigned int* las_t;
__device__ __forceinline__ void gld16(const unsigned short* g, unsigned short* l) {
  __builtin_amdgcn_global_load_lds((gas_t)(const void*)g, (las_t)(void*)l, 16, 0, 0);
}

// ------- 256-thread 64x64 transpose tile (used by prep for W1) -------
__device__ __forceinline__ void tconv_tile(const float* __restrict__ in,
                                           unsigned short* __restrict__ out,
                                           int R, int C, int bx, int by, int z,
                                           float* __restrict__ t) {
  const int r0 = by * 64, c0 = bx * 64;
  const int tr = threadIdx.x / 16;
  const int tc = (threadIdx.x % 16) * 4;
  const float* ip = in + ((size_t)z * R + r0) * (size_t)C + c0;
#pragma unroll
  for (int p = 0; p < 4; ++p) {
    f32x4 v = *(const f32x4*)&ip[(size_t)(p * 16 + tr) * C + tc];
    t[(p * 16 + tr) * 65 + tc + 0] = v[0];
    t[(p * 16 + tr) * 65 + tc + 1] = v[1];
    t[(p * 16 + tr) * 65 + tc + 2] = v[2];
    t[(p * 16 + tr) * 65 + tc + 3] = v[3];
  }
  __syncthreads();
  unsigned short* op = out + ((size_t)z * C + c0) * (size_t)R + r0;
#pragma unroll
  for (int p = 0; p < 4; ++p) {
    int c = p * 16 + tr;
    unsigned int a0 = (unsigned int)f2bf(t[(tc + 0) * 65 + c]) |
                      ((unsigned int)f2bf(t[(tc + 1) * 65 + c]) << 16);
    unsigned int a1 = (unsigned int)f2bf(t[(tc + 2) * 65 + c]) |
                      ((unsigned int)f2bf(t[(tc + 3) * 65 + c]) << 16);
    uint2 val; val.x = a0; val.y = a1;
    *(uint2*)&op[(size_t)c * R + tc] = val;
  }
}

// ------- wave-private 64(i) x 32(h) transpose of W2 -> w2t (no barriers) -------
// Verified rounds 11/12. Scratch stride 37 floats: read banks <=2-way (free).
__device__ __forceinline__ void wave_tconv2(const float* __restrict__ in,
                                            unsigned short* __restrict__ out,
                                            int gidx, float* __restrict__ sc, int lane) {
  const int e = gidx >> 11;                 // 2048 tiles per expert
  const int r = gidx & 2047;
  const int i0 = (r >> 5) * 64, h0 = (r & 31) * 32;
  const float* ip = in + ((size_t)e * INTER + i0) * HID + h0;
  f32x4 v[8];
#pragma unroll
  for (int p = 0; p < 8; ++p)
    v[p] = *(const f32x4*)&ip[(size_t)(p * 8 + (lane >> 3)) * HID + (lane & 7) * 4];
#pragma unroll
  for (int p = 0; p < 8; ++p) {
    const int row = p * 8 + (lane >> 3), col = (lane & 7) * 4;
#pragma unroll
    for (int j = 0; j < 4; ++j) sc[row * 37 + col + j] = v[p][j];
  }
  asm volatile("s_waitcnt lgkmcnt(0)" ::: "memory");
  __builtin_amdgcn_sched_barrier(0);
  unsigned short* op = out + ((size_t)e * HID + h0) * INTER + i0;
#pragma unroll
  for (int p = 0; p < 4; ++p) {
    const int c = p * 8 + (lane >> 3);
    const int r8 = (lane & 7) * 8;
    uint4 w;
    unsigned int* wp = (unsigned int*)&w;
#pragma unroll
    for (int j = 0; j < 4; ++j) {
      unsigned int lo = f2bf(sc[(r8 + 2 * j) * 37 + c]);
      unsigned int hi = f2bf(sc[(r8 + 2 * j + 1) * 37 + c]);
      wp[j] = lo | (hi << 16);
    }
    *(uint4*)&op[(size_t)c * INTER + r8] = w;
  }
}

// ---------------- prep: convx (2048 blocks) + tconv1 (8192) + gating (2048) ----------------
__global__ __launch_bounds__(256) void prep_kernel(const float* __restrict__ x,
                                                   const float* __restrict__ W1,
                                                   const float* __restrict__ wg,
                                                   unsigned short* __restrict__ xb,
                                                   unsigned short* __restrict__ w1t,
                                                   int* __restrict__ tok_e,
                                                   float* __restrict__ tok_w) {
  __shared__ float sh[64 * 65];
  int bid = blockIdx.x;
  if (bid < 2048) {   // ---- convx: x fp32 -> bf16 ----
    size_t i = (size_t)bid * 256 + threadIdx.x;
    f32x4 v = *(const f32x4*)&x[i * 4];
    uint2 r;
    r.x = (unsigned int)f2bf(v[0]) | ((unsigned int)f2bf(v[1]) << 16);
    r.y = (unsigned int)f2bf(v[2]) | ((unsigned int)f2bf(v[3]) << 16);
    *(uint2*)&xb[i * 4] = r;
    return;
  }
  bid -= 2048;
  if (bid < 8192) {   // ---- tconv1: W1 [E][H][I] -> w1t [E][I][H] ----
    tconv_tile(W1, w1t, HID, INTER, bid % 64, (bid / 64) % 16, bid / 1024, sh);
    return;
  }
  bid -= 8192;
  {   // ---- gating for token t = bid ----
    const int t = bid;
    float acc[NE];
#pragma unroll
    for (int e = 0; e < NE; ++e) acc[e] = 0.f;
    for (int k = threadIdx.x; k < HID; k += 256) {
      float xv = x[(size_t)t * HID + k];
#pragma unroll
      for (int e = 0; e < NE; ++e) acc[e] += xv * wg[e * HID + k];
    }
#pragma unroll
    for (int e = 0; e < NE; ++e) {
#pragma unroll
      for (int off = 32; off >= 1; off >>= 1) acc[e] += __shfl_xor(acc[e], off, 64);
    }
    float* red = sh;   // [4][NE]
    const int wave = threadIdx.x >> 6, lane = threadIdx.x & 63;
    if (lane == 0) {
#pragma unroll
      for (int e = 0; e < NE; ++e) red[wave * NE + e] = acc[e];
    }
    __syncthreads();
    if (threadIdx.x == 0) {
      float l[NE];
#pragma unroll
      for (int e = 0; e < NE; ++e)
        l[e] = red[0 * NE + e] + red[1 * NE + e] + red[2 * NE + e] + red[3 * NE + e];
      int i0 = 0;
#pragma unroll
      for (int e = 1; e < NE; ++e) if (l[e] > l[i0]) i0 = e;
      int i1 = -1;
#pragma unroll
      for (int e = 0; e < NE; ++e) {
        if (e == i0) continue;
        if (i1 < 0 || l[e] > l[i1]) i1 = e;
      }
      float e1 = __expf(l[i1] - l[i0]);
      float w0 = 1.f / (1.f + e1);
      tok_e[t * 2 + 0] = i0;
      tok_e[t * 2 + 1] = i1;
      tok_w[t * 2 + 0] = w0;
      tok_w[t * 2 + 1] = 1.f - w0;
    }
  }
}

// ---------------- routing: per-expert compaction (deterministic, single block) ----------------
__global__ __launch_bounds__(512) void routing_kernel(const int* __restrict__ tok_e,
                                                      int* __restrict__ list_tok,
                                                      int* __restrict__ tok_gslot,
                                                      int* __restrict__ offs_out) {
  __shared__ int cnts[NE];
  __shared__ int offs_s[NE + 1];
  const int e = threadIdx.x >> 6, lane = threadIdx.x & 63;
  int c = 0;
  for (int base = 0; base < NTOK; base += 64) {
    int tok = base + lane;
    int e0 = tok_e[tok * 2], e1 = tok_e[tok * 2 + 1];
    bool m = (e0 == e) || (e1 == e);
    unsigned long long mask = __ballot(m);
    c += __popcll(mask);
  }
  if (lane == 0) cnts[e] = c;
  __syncthreads();
  if (threadIdx.x == 0) {
    int o = 0;
    for (int i = 0; i < NE; ++i) { offs_s[i] = o; o += (cnts[i] + 127) & ~127; }
    offs_s[NE] = o;
    for (int i = 0; i <= NE; ++i) offs_out[i] = offs_s[i];
  }
  __syncthreads();
  const int off = offs_s[e];
  int run = 0;
  for (int base = 0; base < NTOK; base += 64) {
    int tok = base + lane;
    int e0 = tok_e[tok * 2], e1 = tok_e[tok * 2 + 1];
    bool m = (e0 == e) || (e1 == e);
    unsigned long long mask = __ballot(m);
    int pos = run + __popcll(mask & ((1ull << lane) - 1ull));
    if (m) {
      int gs = off + pos;
      list_tok[gs] = tok;
      tok_gslot[tok * 2 + ((e0 == e) ? 0 : 1)] = gs;
    }
    run += __popcll(mask);
  }
  const int cnt = cnts[e];
  const int padded = (cnt + 127) & ~127;
  for (int p = cnt + lane; p < padded; p += 64) list_tok[off + p] = 0;
}

// ---------------- grouped GEMM: 128x128 tile, BK=32, ring-3 LDS, counted vmcnt ----------------
// Round-8 verified core (chunk-XOR swizzle, 0 bank conflicts). TCONV: blocks past the
// GEMM grid run wave-private W2 transposes (4 waves x 64x32 tiles per block, barrier-free).
// FIRST: out = bf16 h with bias+GELU; else: out = bf16 partials[ks][row][col] (no bias).
template <int KTOT, int NTOT, bool FIRST, int NSPLIT, bool TCONV>
__global__ __launch_bounds__(256, 3) void moe_gemm(const unsigned short* __restrict__ Abase,
                                                   const unsigned short* __restrict__ Bbase,
                                                   const float* __restrict__ bias,
                                                   const int* __restrict__ list_tok,
                                                   const int* __restrict__ offs,
                                                   void* __restrict__ outp,
                                                   const float* __restrict__ W2f,
                                                   unsigned short* __restrict__ w2t) {
  constexpr int KS = KTOT / NSPLIT;   // K elems per slice
  constexpr int NT = KS / 32;         // K-steps (BK=32)
  constexpr int nM = MAXROWS / 128;
  constexpr int nN = NTOT / 128;
  constexpr int NWG_GEMM = nN * nM * NSPLIT;
  // ring of 3 slots, each: A[128][32] + B[128][32] bf16 = 16KB -> 48KB total
  __shared__ __align__(16) unsigned short lds[3][2][4096];

  const int tid = threadIdx.x;
  const int wave = tid >> 6, lane = tid & 63;

  if (TCONV && (int)blockIdx.x >= NWG_GEMM) {
    // W2 [E][I][H] -> w2t [E][H][I]; 4 wave-tiles per block; scratch 2368 floats/wave
    wave_tconv2(W2f, w2t, ((int)blockIdx.x - NWG_GEMM) * 4 + wave,
                (float*)&lds[0][0][0] + wave * (64 * 37), lane);
    return;
  }

  int wg = blockIdx.x;
  wg = (wg & 7) * (NWG_GEMM >> 3) + (wg >> 3);   // bijective XCD swizzle (NWG_GEMM % 8 == 0)
  const int ks = (NSPLIT > 1) ? (wg / (nM * nN)) : 0;
  const int rem = wg % (nM * nN);
  const int mt = rem % nM;                  // m fastest: neighbors share B panel in L2
  const int nt = rem / nM;
  const int grow0 = mt * 128;
  if (grow0 >= offs[NE]) return;
  int e = 0;
#pragma unroll
  for (int i = 1; i < NE; ++i) if (grow0 >= offs[i]) e = i;
  const int n0 = nt * 128;
  const int k0 = ks * KS;

  // --- staging sources: thread covers rows tid/4 + {0,64}; source chunk pre-swizzled ---
  const int srow = tid >> 2;
  const int skc = (((tid & 3) ^ ((srow >> 1) & 3)) * 8);  // chunk XOR swizzle, shorts
  const unsigned short* ag[2];
  const unsigned short* bg[2];
#pragma unroll
  for (int j = 0; j < 2; ++j) {
    const int row = srow + j * 64;   // (row>>1)&3 identical for j=0,1 (bit6 untouched)
    size_t arow;
    if (FIRST) arow = (size_t)list_tok[grow0 + row] * KTOT;
    else       arow = (size_t)(grow0 + row) * KTOT;
    ag[j] = Abase + arow + k0 + skc;
    bg[j] = Bbase + (size_t)e * NTOT * KTOT + (size_t)(n0 + row) * KTOT + k0 + skc;
  }
  // gld16 LDS dest must be WAVE-UNIFORM base (HW adds lane*16B)
  const int wbase = wave * 512;  // shorts: wave*1024B

  // --- fragment read offsets (shorts), swizzle folded in ---
  const int wm = wave >> 1, wn = wave & 1;
  const int fr = lane & 15;
  const int q = lane >> 4;       // 16B chunk index within the 64B row
  int aoff[4], boff[4];
#pragma unroll
  for (int m = 0; m < 4; ++m) {
    const int row = wm * 64 + m * 16 + fr;
    aoff[m] = row * 32 + ((q ^ ((row >> 1) & 3)) * 8);
  }
#pragma unroll
  for (int n = 0; n < 4; ++n) {
    const int row = wn * 64 + n * 16 + fr;
    boff[n] = row * 32 + ((q ^ ((row >> 1) & 3)) * 8);
  }

  f32x4 acc[4][4] = {};

#define STAGE(S, SLOT)                                             \
  {                                                                \
    gld16(ag[0] + (S) * 32, &lds[SLOT][0][wbase]);                 \
    gld16(ag[1] + (S) * 32, &lds[SLOT][0][wbase + 2048]);          \
    gld16(bg[0] + (S) * 32, &lds[SLOT][1][wbase]);                 \
    gld16(bg[1] + (S) * 32, &lds[SLOT][1][wbase + 2048]);          \
  }

#define KITER(S, SL, DO_STAGE, VMSTR)                                 \
  {                                                                   \
    asm volatile("s_waitcnt vmcnt(" VMSTR ")" ::: "memory");          \
    asm volatile("s_barrier" ::: "memory");                           \
    const unsigned short* A = &lds[SL][0][0];                         \
    const unsigned short* B = &lds[SL][1][0];                         \
    short8v af[4], bf[4];                                             \
    _Pragma("unroll")                                                 \
    for (int m = 0; m < 4; ++m) af[m] = *(const short8v*)&A[aoff[m]]; \
    _Pragma("unroll")                                                 \
    for (int n = 0; n < 4; ++n) bf[n] = *(const short8v*)&B[boff[n]]; \
    if (DO_STAGE) {                                                   \
      int s2 = (SL) + 2; if (s2 >= 3) s2 -= 3;                        \
      STAGE((S) + 2, s2);                                             \
    }                                                                 \
    __builtin_amdgcn_s_setprio(1);                                    \
    _Pragma("unroll")                                                 \
    for (int n = 0; n < 4; ++n)                                       \
      _Pragma("unroll")                                               \
      for (int m = 0; m < 4; ++m)                                     \
        acc[m][n] = __builtin_amdgcn_mfma_f32_16x16x32_bf16(af[m], bf[n], acc[m][n], 0, 0, 0); \
    __builtin_amdgcn_s_setprio(0);                                    \
  }

  // prologue: stage steps 0,1 into slots 0,1 (8 loads outstanding)
  STAGE(0, 0);
  STAGE(1, 1);

  int sl = 0;
  for (int s = 0; s < NT - 2; ++s) {
    KITER(s, sl, true, "4");
    sl = sl + 1; if (sl >= 3) sl = 0;
  }
  KITER(NT - 2, sl, false, "4");
  sl = sl + 1; if (sl >= 3) sl = 0;
  KITER(NT - 1, sl, false, "0");

#undef KITER
#undef STAGE

  const int r4 = lane >> 4;
#pragma unroll
  for (int m = 0; m < 4; ++m) {
#pragma unroll
    for (int n = 0; n < 4; ++n) {
      const int gcol = n0 + wn * 64 + n * 16 + fr;
      float bv = 0.f;
      if (FIRST) bv = bias[e * NTOT + gcol];
#pragma unroll
      for (int r = 0; r < 4; ++r) {
        const int grow = grow0 + wm * 64 + m * 16 + r4 * 4 + r;
        float v = acc[m][n][r] + bv;
        if (FIRST) {
          v = 0.5f * v * (1.0f + erff(v * 0.70710678118654752f));
          ((unsigned short*)outp)[(size_t)grow * NTOT + gcol] = f2bf(v);
        } else {
          // bf16 partial (no bias; reduced in combine)
          ((unsigned short*)outp)[((size_t)ks * MAXROWS + grow) * NTOT + gcol] = f2bf(v);
        }
      }
    }
  }
}

// -------- combine: y[t] = w0*(sum_ks p16[ks][gs0]+b2[e0]) + w1*(...)  (4 bf16 slices) --------
template <int NSPLIT>
__global__ __launch_bounds__(256) void combine_kernel(const unsigned short* __restrict__ part,
                                                      const int* __restrict__ tok_gslot,
                                                      const int* __restrict__ tok_e,
                                                      const float* __restrict__ tok_w,
                                                      const float* __restrict__ b2,
                                                      float* __restrict__ y) {
  const int t = blockIdx.x;
  const int c = threadIdx.x * 4;
  const int gs0 = tok_gslot[t * 2 + 0], gs1 = tok_gslot[t * 2 + 1];
  const int e0 = tok_e[t * 2 + 0], e1 = tok_e[t * 2 + 1];
  const float w0 = tok_w[t * 2 + 0], w1 = tok_w[t * 2 + 1];
  float s0[4] = {0.f, 0.f, 0.f, 0.f}, s1[4] = {0.f, 0.f, 0.f, 0.f};
#pragma unroll
  for (int ks = 0; ks < NSPLIT; ++ks) {
    short4v p0 = *(const short4v*)&part[((size_t)ks * MAXROWS + gs0) * HID + c];
    short4v p1 = *(const short4v*)&part[((size_t)ks * MAXROWS + gs1) * HID + c];
#pragma unroll
    for (int i = 0; i < 4; ++i) {
      s0[i] += bf2f((unsigned short)p0[i]);
      s1[i] += bf2f((unsigned short)p1[i]);
    }
  }
  f32x4 bb0 = *(const f32x4*)&b2[e0 * HID + c];
  f32x4 bb1 = *(const f32x4*)&b2[e1 * HID + c];
  f32x4 r;
#pragma unroll
  for (int i = 0; i < 4; ++i)
    r[i] = w0 * (s0[i] + bb0[i]) + w1 * (s1[i] + bb1[i]);
  *(f32x4*)&y[(size_t)t * HID + c] = r;
}

extern "C" void kernel_launch(void* const* d_in, const int* in_sizes, int n_in,
                              void* d_out, int out_size, void* d_ws, size_t ws_size,
                              hipStream_t stream) {
  const float* x  = (const float*)d_in[0];
  const float* wg = (const float*)d_in[1];
  const float* W1 = (const float*)d_in[2];
  const float* b1 = (const float*)d_in[3];
  const float* W2 = (const float*)d_in[4];
  const float* b2 = (const float*)d_in[5];
  float* y = (float*)d_out;

  unsigned char* ws = (unsigned char*)d_ws;
  size_t off = 0;
  // w1t (live prep->gemm1) aliases part (bf16, 4 slices x 10.5MB = 42MB, live gemm2->combine)
  unsigned short* w1t  = (unsigned short*)(ws + off);
  unsigned short* part = (unsigned short*)(ws + off); off += (size_t)NE * HID * INTER * 2;  // 67MB
  unsigned short* w2t  = (unsigned short*)(ws + off); off += (size_t)NE * INTER * HID * 2;  // 67MB
  unsigned short* xb   = (unsigned short*)(ws + off); off += (size_t)NTOK * HID * 2;        // 4MB
  unsigned short* h    = (unsigned short*)(ws + off); off += (size_t)MAXROWS * INTER * 2;   // 42MB
  int* tok_e           = (int*)(ws + off);            off += NTOK * 2 * 4;
  float* tok_w         = (float*)(ws + off);          off += NTOK * 2 * 4;
  int* tok_gslot       = (int*)(ws + off);            off += NTOK * 2 * 4;
  int* list_tok        = (int*)(ws + off);            off += MAXROWS * 4;
  int* offs            = (int*)(ws + off);            off += 64;
  (void)ws_size; (void)in_sizes; (void)n_in; (void)out_size;

  // prep: convx (2048) + tconv1 (8192) + gating (2048) -- all independent
  prep_kernel<<<2048 + 8192 + 2048, 256, 0, stream>>>(x, W1, wg, xb, w1t, tok_e, tok_w);
  routing_kernel<<<1, 512, 0, stream>>>(tok_e, list_tok, tok_gslot, offs);
  // GEMM1 (1280 blocks) + 4096 wave-tconv2 filler blocks (16384 wave-tiles / 4 waves)
  moe_gemm<HID, INTER, true, 1, true>
      <<<(INTER / 128) * (MAXROWS / 128) + 4096, 256, 0, stream>>>(
          xb, w1t, b1, list_tok, offs, (void*)h, W2, w2t);
  moe_gemm<INTER, HID, false, 4, false>
      <<<(HID / 128) * (MAXROWS / 128) * 4, 256, 0, stream>>>(
          h, w2t, b2, list_tok, offs, (void*)part, nullptr, nullptr);
  combine_kernel<4><<<NTOK, 256, 0, stream>>>(part, tok_gslot, tok_e, tok_w, b2, y);
}

// Round 14
// 214.550 us; speedup vs baseline: 1.2067x; 1.0038x over previous
//
#include <hip/hip_runtime.h>
#include <hip/hip_bf16.h>

#define HID 1024
#define INTER 4096
#define NE 8
#define NTOK 2048
#define MAXROWS 5120   // 4096 pairs + 8*127 pad, rounded up

typedef __attribute__((ext_vector_type(8))) short short8v;
typedef __attribute__((ext_vector_type(4))) short short4v;
typedef __attribute__((ext_vector_type(4))) float f32x4;

__device__ __forceinline__ unsigned short f2bf(float f) {
  unsigned int u = __builtin_bit_cast(unsigned int, f);
  u = (u + 0x7FFFu + ((u >> 16) & 1u)) >> 16;
  return (unsigned short)u;
}
__device__ __forceinline__ float bf2f(unsigned short s) {
  unsigned int u = ((unsigned int)s) << 16;
  return __builtin_bit_cast(float, u);
}

typedef const __attribute__((address_space(1))) unsigned int* gas_t;
typedef __attribute__((address_space(3))) unsigned int* las_t;
__device__ __forceinline__ void gld16(const unsigned short* g, unsigned short* l) {
  __builtin_amdgcn_global_load_lds((gas_t)(const void*)g, (las_t)(void*)l, 16, 0, 0);
}

// ------- 256-thread 64x64 transpose tile (used by prep for W1) -------
// fp32 source loads are NONTEMPORAL: stream-once data must not evict w1t/h/w2t from L3.
__device__ __forceinline__ void tconv_tile(const float* __restrict__ in,
                                           unsigned short* __restrict__ out,
                                           int R, int C, int bx, int by, int z,
                                           float* __restrict__ t) {
  const int r0 = by * 64, c0 = bx * 64;
  const int tr = threadIdx.x / 16;
  const int tc = (threadIdx.x % 16) * 4;
  const float* ip = in + ((size_t)z * R + r0) * (size_t)C + c0;
#pragma unroll
  for (int p = 0; p < 4; ++p) {
    f32x4 v = __builtin_nontemporal_load((const f32x4*)&ip[(size_t)(p * 16 + tr) * C + tc]);
    t[(p * 16 + tr) * 65 + tc + 0] = v[0];
    t[(p * 16 + tr) * 65 + tc + 1] = v[1];
    t[(p * 16 + tr) * 65 + tc + 2] = v[2];
    t[(p * 16 + tr) * 65 + tc + 3] = v[3];
  }
  __syncthreads();
  unsigned short* op = out + ((size_t)z * C + c0) * (size_t)R + r0;
#pragma unroll
  for (int p = 0; p < 4; ++p) {
    int c = p * 16 + tr;
    unsigned int a0 = (unsigned int)f2bf(t[(tc + 0) * 65 + c]) |
                      ((unsigned int)f2bf(t[(tc + 1) * 65 + c]) << 16);
    unsigned int a1 = (unsigned int)f2bf(t[(tc + 2) * 65 + c]) |
                      ((unsigned int)f2bf(t[(tc + 3) * 65 + c]) << 16);
    uint2 val; val.x = a0; val.y = a1;
    *(uint2*)&op[(size_t)c * R + tc] = val;
  }
}

// ------- wave-private 64(i) x 32(h) transpose of W2 -> w2t (no barriers) -------
// Verified rounds 11/12. W2 fp32 loads NONTEMPORAL (stream-once; protect L3 residency
// of h/w2t for GEMM2). Scratch stride 37 floats: <=2-way banks (free).
__device__ __forceinline__ void wave_tconv2(const float* __restrict__ in,
                                            unsigned short* __restrict__ out,
                                            int gidx, float* __restrict__ sc, int lane) {
  const int e = gidx >> 11;                 // 2048 tiles per expert
  const int r = gidx & 2047;
  const int i0 = (r >> 5) * 64, h0 = (r & 31) * 32;
  const float* ip = in + ((size_t)e * INTER + i0) * HID + h0;
  f32x4 v[8];
#pragma unroll
  for (int p = 0; p < 8; ++p)
    v[p] = __builtin_nontemporal_load(
        (const f32x4*)&ip[(size_t)(p * 8 + (lane >> 3)) * HID + (lane & 7) * 4]);
#pragma unroll
  for (int p = 0; p < 8; ++p) {
    const int row = p * 8 + (lane >> 3), col = (lane & 7) * 4;
#pragma unroll
    for (int j = 0; j < 4; ++j) sc[row * 37 + col + j] = v[p][j];
  }
  asm volatile("s_waitcnt lgkmcnt(0)" ::: "memory");
  __builtin_amdgcn_sched_barrier(0);
  unsigned short* op = out + ((size_t)e * HID + h0) * INTER + i0;
#pragma unroll
  for (int p = 0; p < 4; ++p) {
    const int c = p * 8 + (lane >> 3);
    const int r8 = (lane & 7) * 8;
    uint4 w;
    unsigned int* wp = (unsigned int*)&w;
#pragma unroll
    for (int j = 0; j < 4; ++j) {
      unsigned int lo = f2bf(sc[(r8 + 2 * j) * 37 + c]);
      unsigned int hi = f2bf(sc[(r8 + 2 * j + 1) * 37 + c]);
      wp[j] = lo | (hi << 16);
    }
    *(uint4*)&op[(size_t)c * INTER + r8] = w;
  }
}

// ---------------- prep: convx (2048 blocks) + tconv1 (8192) + gating (2048) ----------------
__global__ __launch_bounds__(256) void prep_kernel(const float* __restrict__ x,
                                                   const float* __restrict__ W1,
                                                   const float* __restrict__ wg,
                                                   unsigned short* __restrict__ xb,
                                                   unsigned short* __restrict__ w1t,
                                                   int* __restrict__ tok_e,
                                                   float* __restrict__ tok_w) {
  __shared__ float sh[64 * 65];
  int bid = blockIdx.x;
  if (bid < 2048) {   // ---- convx: x fp32 -> bf16 ----
    size_t i = (size_t)bid * 256 + threadIdx.x;
    f32x4 v = *(const f32x4*)&x[i * 4];
    uint2 r;
    r.x = (unsigned int)f2bf(v[0]) | ((unsigned int)f2bf(v[1]) << 16);
    r.y = (unsigned int)f2bf(v[2]) | ((unsigned int)f2bf(v[3]) << 16);
    *(uint2*)&xb[i * 4] = r;
    return;
  }
  bid -= 2048;
  if (bid < 8192) {   // ---- tconv1: W1 [E][H][I] -> w1t [E][I][H] ----
    tconv_tile(W1, w1t, HID, INTER, bid % 64, (bid / 64) % 16, bid / 1024, sh);
    return;
  }
  bid -= 8192;
  {   // ---- gating for token t = bid ----
    const int t = bid;
    float acc[NE];
#pragma unroll
    for (int e = 0; e < NE; ++e) acc[e] = 0.f;
    for (int k = threadIdx.x; k < HID; k += 256) {
      float xv = x[(size_t)t * HID + k];
#pragma unroll
      for (int e = 0; e < NE; ++e) acc[e] += xv * wg[e * HID + k];
    }
#pragma unroll
    for (int e = 0; e < NE; ++e) {
#pragma unroll
      for (int off = 32; off >= 1; off >>= 1) acc[e] += __shfl_xor(acc[e], off, 64);
    }
    float* red = sh;   // [4][NE]
    const int wave = threadIdx.x >> 6, lane = threadIdx.x & 63;
    if (lane == 0) {
#pragma unroll
      for (int e = 0; e < NE; ++e) red[wave * NE + e] = acc[e];
    }
    __syncthreads();
    if (threadIdx.x == 0) {
      float l[NE];
#pragma unroll
      for (int e = 0; e < NE; ++e)
        l[e] = red[0 * NE + e] + red[1 * NE + e] + red[2 * NE + e] + red[3 * NE + e];
      int i0 = 0;
#pragma unroll
      for (int e = 1; e < NE; ++e) if (l[e] > l[i0]) i0 = e;
      int i1 = -1;
#pragma unroll
      for (int e = 0; e < NE; ++e) {
        if (e == i0) continue;
        if (i1 < 0 || l[e] > l[i1]) i1 = e;
      }
      float e1 = __expf(l[i1] - l[i0]);
      float w0 = 1.f / (1.f + e1);
      tok_e[t * 2 + 0] = i0;
      tok_e[t * 2 + 1] = i1;
      tok_w[t * 2 + 0] = w0;
      tok_w[t * 2 + 1] = 1.f - w0;
    }
  }
}

// ---------------- routing: per-expert compaction (deterministic, single block) ----------------
__global__ __launch_bounds__(512) void routing_kernel(const int* __restrict__ tok_e,
                                                      int* __restrict__ list_tok,
                                                      int* __restrict__ tok_gslot,
                                                      int* __restrict__ offs_out) {
  __shared__ int cnts[NE];
  __shared__ int offs_s[NE + 1];
  const int e = threadIdx.x >> 6, lane = threadIdx.x & 63;
  int c = 0;
  for (int base = 0; base < NTOK; base += 64) {
    int tok = base + lane;
    int e0 = tok_e[tok * 2], e1 = tok_e[tok * 2 + 1];
    bool m = (e0 == e) || (e1 == e);
    unsigned long long mask = __ballot(m);
    c += __popcll(mask);
  }
  if (lane == 0) cnts[e] = c;
  __syncthreads();
  if (threadIdx.x == 0) {
    int o = 0;
    for (int i = 0; i < NE; ++i) { offs_s[i] = o; o += (cnts[i] + 127) & ~127; }
    offs_s[NE] = o;
    for (int i = 0; i <= NE; ++i) offs_out[i] = offs_s[i];
  }
  __syncthreads();
  const int off = offs_s[e];
  int run = 0;
  for (int base = 0; base < NTOK; base += 64) {
    int tok = base + lane;
    int e0 = tok_e[tok * 2], e1 = tok_e[tok * 2 + 1];
    bool m = (e0 == e) || (e1 == e);
    unsigned long long mask = __ballot(m);
    int pos = run + __popcll(mask & ((1ull << lane) - 1ull));
    if (m) {
      int gs = off + pos;
      list_tok[gs] = tok;
      tok_gslot[tok * 2 + ((e0 == e) ? 0 : 1)] = gs;
    }
    run += __popcll(mask);
  }
  const int cnt = cnts[e];
  const int padded = (cnt + 127) & ~127;
  for (int p = cnt + lane; p < padded; p += 64) list_tok[off + p] = 0;
}

// ---------------- grouped GEMM: 128x128 tile, BK=32, ring-3 LDS, counted vmcnt ----------------
// Round-8 verified core (chunk-XOR swizzle, 0 bank conflicts). TCONV: blocks past the
// GEMM grid run wave-private W2 transposes (4 waves x 64x32 tiles per block, barrier-free,
// nontemporal fp32 reads).
// FIRST: out = bf16 h with bias+GELU; else: out = bf16 partials[ks][row][col] (no bias).
template <int KTOT, int NTOT, bool FIRST, int NSPLIT, bool TCONV>
__global__ __launch_bounds__(256, 3) void moe_gemm(const unsigned short* __restrict__ Abase,
                                                   const unsigned short* __restrict__ Bbase,
                                                   const float* __restrict__ bias,
                                                   const int* __restrict__ list_tok,
                                                   const int* __restrict__ offs,
                                                   void* __restrict__ outp,
                                                   const float* __restrict__ W2f,
                                                   unsigned short* __restrict__ w2t) {
  constexpr int KS = KTOT / NSPLIT;   // K elems per slice
  constexpr int NT = KS / 32;         // K-steps (BK=32)
  constexpr int nM = MAXROWS / 128;
  constexpr int nN = NTOT / 128;
  constexpr int NWG_GEMM = nN * nM * NSPLIT;
  // ring of 3 slots, each: A[128][32] + B[128][32] bf16 = 16KB -> 48KB total
  __shared__ __align__(16) unsigned short lds[3][2][4096];

  const int tid = threadIdx.x;
  const int wave = tid >> 6, lane = tid & 63;

  if (TCONV && (int)blockIdx.x >= NWG_GEMM) {
    // W2 [E][I][H] -> w2t [E][H][I]; 4 wave-tiles per block; scratch 2368 floats/wave
    wave_tconv2(W2f, w2t, ((int)blockIdx.x - NWG_GEMM) * 4 + wave,
                (float*)&lds[0][0][0] + wave * (64 * 37), lane);
    return;
  }

  int wg = blockIdx.x;
  wg = (wg & 7) * (NWG_GEMM >> 3) + (wg >> 3);   // bijective XCD swizzle (NWG_GEMM % 8 == 0)
  const int ks = (NSPLIT > 1) ? (wg / (nM * nN)) : 0;
  const int rem = wg % (nM * nN);
  const int mt = rem % nM;                  // m fastest: neighbors share B panel in L2
  const int nt = rem / nM;
  const int grow0 = mt * 128;
  if (grow0 >= offs[NE]) return;
  int e = 0;
#pragma unroll
  for (int i = 1; i < NE; ++i) if (grow0 >= offs[i]) e = i;
  const int n0 = nt * 128;
  const int k0 = ks * KS;

  // --- staging sources: thread covers rows tid/4 + {0,64}; source chunk pre-swizzled ---
  const int srow = tid >> 2;
  const int skc = (((tid & 3) ^ ((srow >> 1) & 3)) * 8);  // chunk XOR swizzle, shorts
  const unsigned short* ag[2];
  const unsigned short* bg[2];
#pragma unroll
  for (int j = 0; j < 2; ++j) {
    const int row = srow + j * 64;   // (row>>1)&3 identical for j=0,1 (bit6 untouched)
    size_t arow;
    if (FIRST) arow = (size_t)list_tok[grow0 + row] * KTOT;
    else       arow = (size_t)(grow0 + row) * KTOT;
    ag[j] = Abase + arow + k0 + skc;
    bg[j] = Bbase + (size_t)e * NTOT * KTOT + (size_t)(n0 + row) * KTOT + k0 + skc;
  }
  // gld16 LDS dest must be WAVE-UNIFORM base (HW adds lane*16B)
  const int wbase = wave * 512;  // shorts: wave*1024B

  // --- fragment read offsets (shorts), swizzle folded in ---
  const int wm = wave >> 1, wn = wave & 1;
  const int fr = lane & 15;
  const int q = lane >> 4;       // 16B chunk index within the 64B row
  int aoff[4], boff[4];
#pragma unroll
  for (int m = 0; m < 4; ++m) {
    const int row = wm * 64 + m * 16 + fr;
    aoff[m] = row * 32 + ((q ^ ((row >> 1) & 3)) * 8);
  }
#pragma unroll
  for (int n = 0; n < 4; ++n) {
    const int row = wn * 64 + n * 16 + fr;
    boff[n] = row * 32 + ((q ^ ((row >> 1) & 3)) * 8);
  }

  f32x4 acc[4][4] = {};

#define STAGE(S, SLOT)                                             \
  {                                                                \
    gld16(ag[0] + (S) * 32, &lds[SLOT][0][wbase]);                 \
    gld16(ag[1] + (S) * 32, &lds[SLOT][0][wbase + 2048]);          \
    gld16(bg[0] + (S) * 32, &lds[SLOT][1][wbase]);                 \
    gld16(bg[1] + (S) * 32, &lds[SLOT][1][wbase + 2048]);          \
  }

#define KITER(S, SL, DO_STAGE, VMSTR)                                 \
  {                                                                   \
    asm volatile("s_waitcnt vmcnt(" VMSTR ")" ::: "memory");          \
    asm volatile("s_barrier" ::: "memory");                           \
    const unsigned short* A = &lds[SL][0][0];                         \
    const unsigned short* B = &lds[SL][1][0];                         \
    short8v af[4], bf[4];                                             \
    _Pragma("unroll")                                                 \
    for (int m = 0; m < 4; ++m) af[m] = *(const short8v*)&A[aoff[m]]; \
    _Pragma("unroll")                                                 \
    for (int n = 0; n < 4; ++n) bf[n] = *(const short8v*)&B[boff[n]]; \
    if (DO_STAGE) {                                                   \
      int s2 = (SL) + 2; if (s2 >= 3) s2 -= 3;                        \
      STAGE((S) + 2, s2);                                             \
    }                                                                 \
    __builtin_amdgcn_s_setprio(1);                                    \
    _Pragma("unroll")                                                 \
    for (int n = 0; n < 4; ++n)                                       \
      _Pragma("unroll")                                               \
      for (int m = 0; m < 4; ++m)                                     \
        acc[m][n] = __builtin_amdgcn_mfma_f32_16x16x32_bf16(af[m], bf[n], acc[m][n], 0, 0, 0); \
    __builtin_amdgcn_s_setprio(0);                                    \
  }

  // prologue: stage steps 0,1 into slots 0,1 (8 loads outstanding)
  STAGE(0, 0);
  STAGE(1, 1);

  int sl = 0;
  for (int s = 0; s < NT - 2; ++s) {
    KITER(s, sl, true, "4");
    sl = sl + 1; if (sl >= 3) sl = 0;
  }
  KITER(NT - 2, sl, false, "4");
  sl = sl + 1; if (sl >= 3) sl = 0;
  KITER(NT - 1, sl, false, "0");

#undef KITER
#undef STAGE

  const int r4 = lane >> 4;
#pragma unroll
  for (int m = 0; m < 4; ++m) {
#pragma unroll
    for (int n = 0; n < 4; ++n) {
      const int gcol = n0 + wn * 64 + n * 16 + fr;
      float bv = 0.f;
      if (FIRST) bv = bias[e * NTOT + gcol];
#pragma unroll
      for (int r = 0; r < 4; ++r) {
        const int grow = grow0 + wm * 64 + m * 16 + r4 * 4 + r;
        float v = acc[m][n][r] + bv;
        if (FIRST) {
          v = 0.5f * v * (1.0f + erff(v * 0.70710678118654752f));
          ((unsigned short*)outp)[(size_t)grow * NTOT + gcol] = f2bf(v);
        } else {
          // bf16 partial (no bias; reduced in combine)
          ((unsigned short*)outp)[((size_t)ks * MAXROWS + grow) * NTOT + gcol] = f2bf(v);
        }
      }
    }
  }
}

// -------- combine: y[t] = w0*(sum_ks p16[ks][gs0]+b2[e0]) + w1*(...)  (4 bf16 slices) --------
template <int NSPLIT>
__global__ __launch_bounds__(256) void combine_kernel(const unsigned short* __restrict__ part,
                                                      const int* __restrict__ tok_gslot,
                                                      const int* __restrict__ tok_e,
                                                      const float* __restrict__ tok_w,
                                                      const float* __restrict__ b2,
                                                      float* __restrict__ y) {
  const int t = blockIdx.x;
  const int c = threadIdx.x * 4;
  const int gs0 = tok_gslot[t * 2 + 0], gs1 = tok_gslot[t * 2 + 1];
  const int e0 = tok_e[t * 2 + 0], e1 = tok_e[t * 2 + 1];
  const float w0 = tok_w[t * 2 + 0], w1 = tok_w[t * 2 + 1];
  float s0[4] = {0.f, 0.f, 0.f, 0.f}, s1[4] = {0.f, 0.f, 0.f, 0.f};
#pragma unroll
  for (int ks = 0; ks < NSPLIT; ++ks) {
    short4v p0 = *(const short4v*)&part[((size_t)ks * MAXROWS + gs0) * HID + c];
    short4v p1 = *(const short4v*)&part[((size_t)ks * MAXROWS + gs1) * HID + c];
#pragma unroll
    for (int i = 0; i < 4; ++i) {
      s0[i] += bf2f((unsigned short)p0[i]);
      s1[i] += bf2f((unsigned short)p1[i]);
    }
  }
  f32x4 bb0 = *(const f32x4*)&b2[e0 * HID + c];
  f32x4 bb1 = *(const f32x4*)&b2[e1 * HID + c];
  f32x4 r;
#pragma unroll
  for (int i = 0; i < 4; ++i)
    r[i] = w0 * (s0[i] + bb0[i]) + w1 * (s1[i] + bb1[i]);
  *(f32x4*)&y[(size_t)t * HID + c] = r;
}

extern "C" void kernel_launch(void* const* d_in, const int* in_sizes, int n_in,
                              void* d_out, int out_size, void* d_ws, size_t ws_size,
                              hipStream_t stream) {
  const float* x  = (const float*)d_in[0];
  const float* wg = (const float*)d_in[1];
  const float* W1 = (const float*)d_in[2];
  const float* b1 = (const float*)d_in[3];
  const float* W2 = (const float*)d_in[4];
  const float* b2 = (const float*)d_in[5];
  float* y = (float*)d_out;

  unsigned char* ws = (unsigned char*)d_ws;
  size_t off = 0;
  // w1t (live prep->gemm1) aliases part (bf16, 4 slices x 10.5MB = 42MB, live gemm2->combine)
  unsigned short* w1t  = (unsigned short*)(ws + off);
  unsigned short* part = (unsigned short*)(ws + off); off += (size_t)NE * HID * INTER * 2;  // 67MB
  unsigned short* w2t  = (unsigned short*)(ws + off); off += (size_t)NE * INTER * HID * 2;  // 67MB
  unsigned short* xb   = (unsigned short*)(ws + off); off += (size_t)NTOK * HID * 2;        // 4MB
  unsigned short* h    = (unsigned short*)(ws + off); off += (size_t)MAXROWS * INTER * 2;   // 42MB
  int* tok_e           = (int*)(ws + off);            off += NTOK * 2 * 4;
  float* tok_w         = (float*)(ws + off);          off += NTOK * 2 * 4;
  int* tok_gslot       = (int*)(ws + off);            off += NTOK * 2 * 4;
  int* list_tok        = (int*)(ws + off);            off += MAXROWS * 4;
  int* offs            = (int*)(ws + off);            off += 64;
  (void)ws_size; (void)in_sizes; (void)n_in; (void)out_size;

  // prep: convx (2048) + tconv1 (8192) + gating (2048) -- all independent
  prep_kernel<<<2048 + 8192 + 2048, 256, 0, stream>>>(x, W1, wg, xb, w1t, tok_e, tok_w);
  routing_kernel<<<1, 512, 0, stream>>>(tok_e, list_tok, tok_gslot, offs);
  // GEMM1 (1280 blocks) + 4096 wave-tconv2 filler blocks (16384 wave-tiles / 4 waves)
  moe_gemm<HID, INTER, true, 1, true>
      <<<(INTER / 128) * (MAXROWS / 128) + 4096, 256, 0, stream>>>(
          xb, w1t, b1, list_tok, offs, (void*)h, W2, w2t);
  moe_gemm<INTER, HID, false, 4, false>
      <<<(HID / 128) * (MAXROWS / 128) * 4, 256, 0, stream>>>(
          h, w2t, b2, list_tok, offs, (void*)part, nullptr, nullptr);
  combine_kernel<4><<<NTOK, 256, 0, stream>>>(part, tok_gslot, tok_e, tok_w, b2, y);
}